// Round 8
// baseline (473.522 us; speedup 1.0000x reference)
//
#include <hip/hip_runtime.h>
#include <hip/hip_fp16.h>
#include <stdint.h>

#define NN 100000
#define NB 512
#define BUCKET 196   // ceil(NN/NB)
#define TILE 4096
#define EPT 16       // TILE / 256

typedef _Float16 f16x8 __attribute__((ext_vector_type(8)));
typedef float f32x4  __attribute__((ext_vector_type(4)));

__device__ __forceinline__ int edge_at(const void* p, int f64, long long idx){
    return f64 ? (int)((const long long*)p)[idx] : ((const int*)p)[idx];
}

// ---------- graph preprocessing ----------

__global__ void k_detect(const void* __restrict__ ep, int* flag, long long nwords, long long nn){
    __shared__ int bad;
    if (threadIdx.x == 0) bad = 0;
    __syncthreads();
    const long long* p = (const long long*)ep;
    for (long long i = threadIdx.x; i < 1024 && i < nwords; i += blockDim.x){
        long long v = p[i];
        if (v < 0 || v >= nn) atomicOr(&bad, 1);
    }
    __syncthreads();
    if (threadIdx.x == 0) flag[0] = bad ? 0 : 1;  // 1 => int64
}

__global__ __launch_bounds__(256) void k_hist(const void* __restrict__ ep, const int* __restrict__ flag,
                                              int* __restrict__ gbcnt, int E){
    __shared__ int h[NB];
    for (int i = threadIdx.x; i < NB; i += 256) h[i] = 0;
    __syncthreads();
    int f = flag[0];
    for (long long e = blockIdx.x * 256 + threadIdx.x; e < E; e += (long long)gridDim.x * 256){
        int d = edge_at(ep, f, (long long)E + e);
        atomicAdd(&h[d / BUCKET], 1);
    }
    __syncthreads();
    for (int i = threadIdx.x; i < NB; i += 256)
        if (h[i]) atomicAdd(&gbcnt[i], h[i]);
}

__global__ void k_scanB(const int* __restrict__ gbcnt, int* __restrict__ bbase,
                        int* __restrict__ bcursor, int E){
    __shared__ int sh[NB];
    int t = threadIdx.x;
    int own = gbcnt[t];
    sh[t] = own; __syncthreads();
    for (int off = 1; off < NB; off <<= 1){
        int u = (t >= off) ? sh[t - off] : 0;
        __syncthreads();
        sh[t] += u;
        __syncthreads();
    }
    int excl = sh[t] - own;
    bbase[t] = excl;
    bcursor[t] = excl;
    if (t == NB - 1) bbase[NB] = excl + own;
    (void)E;
}

__global__ __launch_bounds__(256) void k_scatter(const void* __restrict__ ep, const int* __restrict__ flag,
                                                 int* __restrict__ bcursor, uint2* __restrict__ rec, int E){
    __shared__ int h[NB];
    __shared__ int gb[NB];
    int f = flag[0];
    long long base = (long long)blockIdx.x * TILE;
    for (int i = threadIdx.x; i < NB; i += 256) h[i] = 0;
    __syncthreads();
    int s[EPT], d[EPT], r[EPT], bb[EPT];
    #pragma unroll
    for (int j = 0; j < EPT; ++j){
        long long e = base + j * 256 + threadIdx.x;
        if (e < E){
            s[j]  = edge_at(ep, f, e);
            d[j]  = edge_at(ep, f, (long long)E + e);
            bb[j] = d[j] / BUCKET;
            r[j]  = atomicAdd(&h[bb[j]], 1);
        }
    }
    __syncthreads();
    for (int i = threadIdx.x; i < NB; i += 256)
        gb[i] = h[i] ? atomicAdd(&bcursor[i], h[i]) : 0;
    __syncthreads();
    #pragma unroll
    for (int j = 0; j < EPT; ++j){
        long long e = base + j * 256 + threadIdx.x;
        if (e < E) rec[gb[bb[j]] + r[j]] = make_uint2((unsigned)s[j], (unsigned)d[j]);
    }
}

__global__ __launch_bounds__(256) void k_csr(const uint2* __restrict__ rec, const int* __restrict__ bbase,
                                             int* __restrict__ rp, int* __restrict__ col,
                                             float* __restrict__ dinv, int E){
    int b = blockIdx.x;
    int t = threadIdx.x;
    if (b == 0 && t == 0) rp[NN] = E;
    int d0 = b * BUCKET;
    if (d0 >= NN) return;
    int e0 = bbase[b], e1 = bbase[b + 1];
    __shared__ int h[BUCKET];
    __shared__ int sc[256];
    __shared__ int cur[BUCKET];
    for (int i = t; i < BUCKET; i += 256) h[i] = 0;
    __syncthreads();
    for (int e = e0 + t; e < e1; e += 256)
        atomicAdd(&h[rec[e].y - d0], 1);
    __syncthreads();
    int own = (t < BUCKET) ? h[t] : 0;
    sc[t] = own; __syncthreads();
    for (int off = 1; off < 256; off <<= 1){
        int u = (t >= off) ? sc[t - off] : 0;
        __syncthreads();
        sc[t] += u;
        __syncthreads();
    }
    int excl = sc[t] - own;
    if (t < BUCKET && d0 + t < NN){
        rp[d0 + t]   = e0 + excl;
        cur[t]       = e0 + excl;
        dinv[d0 + t] = rsqrtf((float)(own + 1));
    }
    __syncthreads();
    for (int e = e0 + t; e < e1; e += 256){
        uint2 u = rec[e];
        int p = atomicAdd(&cur[u.y - d0], 1);
        col[p] = (int)u.x;
    }
}

// ---------- GEMM1 via single-term fp16 MFMA ----------

// Pack W1 (165x128 fp32, zero-padded K to 192) into fragment-ready fp16.
__global__ __launch_bounds__(256) void k_prepW(const float* __restrict__ W1, _Float16* __restrict__ Bf){
    int q = blockIdx.x * 256 + threadIdx.x;   // 192*128 = 24576
    if (q >= 192 * 128) return;
    int k = q >> 7, c = q & 127;
    float w = (k < 165) ? W1[k * 128 + c] : 0.0f;
    int tt = k >> 5, kk = k & 31;
    int lane = ((kk >> 3) << 4) + (c & 15);
    int j = kk & 7;
    int f = c >> 4;
    int idx = (((tt * 8 + f) * 64 + lane) << 3) + j;
    Bf[idx] = (_Float16)w;
}

// C = (x @ W1) * dinv, stored fp16 (full-line coalesced epilogue via LDS).
#define ASTRIDE 200   // fp16 elems; 400B row stride
#define CSTRIDE 136   // fp16 elems; C-tile stride (16B-aligned rows)
__global__ __launch_bounds__(256, 4) void k_gemm1(const float* __restrict__ x,
                                                  const _Float16* __restrict__ Bf16,
                                                  const float* __restrict__ dinv,
                                                  _Float16* __restrict__ xws, int n){
    __shared__ _Float16 Ah[64 * ASTRIDE];
    int t = threadIdx.x;
    int w = t >> 6, lane = t & 63;
    int i0 = blockIdx.x * 64;

    // zero ONLY K-pad columns 165..191 (no overlap with staging -> no race)
    for (int q = t; q < 64 * 27; q += 256){
        int r = q / 27, k = 165 + (q - r * 27);
        Ah[r * ASTRIDE + k] = (_Float16)0.0f;
    }

    // B fragments -> registers (12 x b128), independent of LDS staging
    f16x8 Bf[6][2];
    #pragma unroll
    for (int tt = 0; tt < 6; ++tt)
        #pragma unroll
        for (int cf = 0; cf < 2; ++cf)
            Bf[tt][cf] = *(const f16x8*)&Bf16[((tt * 8 + (w * 2 + cf)) * 64 + lane) << 3];

    // stage A tile: 64*165 = 10560 elems, flat coalesced, 7 batches of 6 indep loads
    {
        const float* src = x + (size_t)i0 * 165;
        int nElem = n - i0;
        nElem = (nElem > 64 ? 64 : nElem) * 165;
        #pragma unroll
        for (int b = 0; b < 7; ++b){
            float v[6];
            #pragma unroll
            for (int u = 0; u < 6; ++u){
                int idx = t + (b * 6 + u) * 256;
                v[u] = (idx < nElem) ? src[idx] : 0.0f;
            }
            #pragma unroll
            for (int u = 0; u < 6; ++u){
                int idx = t + (b * 6 + u) * 256;
                if (idx < 64 * 165){
                    int r = idx / 165;          // magic-mul
                    int k = idx - r * 165;
                    Ah[r * ASTRIDE + k] = (_Float16)v[u];
                }
            }
        }
    }

    f32x4 acc[4][2];
    #pragma unroll
    for (int m = 0; m < 4; ++m){ acc[m][0] = (f32x4)0.0f; acc[m][1] = (f32x4)0.0f; }

    __syncthreads();

    int rl = lane & 15, kl = (lane >> 4) * 8;
    #pragma unroll
    for (int tt = 0; tt < 6; ++tt){
        f16x8 ah[4];
        #pragma unroll
        for (int m = 0; m < 4; ++m)
            ah[m] = *(const f16x8*)&Ah[(m * 16 + rl) * ASTRIDE + tt * 32 + kl];
        #pragma unroll
        for (int m = 0; m < 4; ++m)
            #pragma unroll
            for (int cf = 0; cf < 2; ++cf)
                acc[m][cf] = __builtin_amdgcn_mfma_f32_16x16x32_f16(ah[m], Bf[tt][cf], acc[m][cf], 0, 0, 0);
    }

    // epilogue: stage C in LDS (reuse Ah), then full-line coalesced global writes
    __syncthreads();           // all frag reads of Ah done
    _Float16* Cs = (_Float16*)Ah;
    #pragma unroll
    for (int m = 0; m < 4; ++m){
        int rloc = m * 16 + (lane >> 4) * 4;
        #pragma unroll
        for (int r = 0; r < 4; ++r){
            int row = i0 + rloc + r;
            float dvv = (row < n) ? dinv[row] : 0.0f;
            #pragma unroll
            for (int cf = 0; cf < 2; ++cf){
                int colg = w * 32 + cf * 16 + (lane & 15);
                Cs[(rloc + r) * CSTRIDE + colg] = (_Float16)(acc[m][cf][r] * dvv);
            }
        }
    }
    __syncthreads();
    int nrow = (i0 + 64 <= n) ? 64 : (n - i0);
    for (int q = t; q < nrow * 16; q += 256){        // 16 uint4 = 128 fp16 per row
        int row = q >> 4, cw = q & 15;
        uint4 vv = *(const uint4*)&Cs[row * CSTRIDE + cw * 8];
        *(uint4*)&xws[((size_t)(i0 + row)) * 128 + cw * 8] = vv;
    }
}

// ---------- SpMM layer 1: XCD feature-sharded gather ----------
// Grid: (node-group x 8 slices). slice = blockIdx&7 -> round-robin XCD; each
// XCD gathers only its 3.2MB slice of xws (L2-resident). Per (node,slice):
// partial relu+W2 dot, atomicAdd into hw2s (zero-initialized).
__global__ __launch_bounds__(256) void k_spmm1(const __half2* __restrict__ xwh, const int* __restrict__ rp,
                                               const int* __restrict__ col, const float* __restrict__ dinv,
                                               const float* __restrict__ b1, const float* __restrict__ W2,
                                               float* __restrict__ hw2s, int n){
    int b = blockIdx.x;
    int slice = b & 7;
    int node = (b >> 3) * 4 + (threadIdx.x >> 6);
    if (node >= n) return;
    int lane = threadIdx.x & 63;
    int eg = lane >> 3, fp = lane & 7;
    int e0 = rp[node], e1 = rp[node + 1];
    float di = dinv[node];
    const __half2* base = xwh + slice * 8 + fp;
    __half2 zero = __float2half2_rn(0.0f);
    __half2 a = (eg == 0) ? base[(size_t)node * 64] : zero;   // self loop once
    for (int e = e0; e < e1; e += 16){
        int i1 = e + eg, i2 = e + 8 + eg;
        bool ok1 = i1 < e1, ok2 = i2 < e1;
        int c1 = ok1 ? __builtin_nontemporal_load(&col[i1]) : 0;
        int c2 = ok2 ? __builtin_nontemporal_load(&col[i2]) : 0;
        __half2 v1 = base[(size_t)c1 * 64];
        __half2 v2 = base[(size_t)c2 * 64];
        if (ok1) a = __hadd2(a, v1);
        if (ok2) a = __hadd2(a, v2);
    }
    // sum across the 8 edge-groups (lanes differing in bits 3..5)
    #pragma unroll
    for (int off = 8; off < 64; off <<= 1){
        int ai = __shfl_xor(*(int*)&a, off);
        a = __hadd2(a, *(__half2*)&ai);
    }
    float a0 = __low2float(a), a1 = __high2float(a);
    int f0 = slice * 16 + 2 * fp;
    float2 bb = *(const float2*)(b1 + f0);
    float h0 = fmaxf(di * a0 + bb.x, 0.0f);
    float h1 = fmaxf(di * a1 + bb.y, 0.0f);
    float4 wv = *(const float4*)(W2 + 2 * f0);
    float s0 = h0 * wv.x + h1 * wv.z;
    float s1 = h0 * wv.y + h1 * wv.w;
    #pragma unroll
    for (int off = 1; off < 8; off <<= 1){
        s0 += __shfl_xor(s0, off);
        s1 += __shfl_xor(s1, off);
    }
    if (lane == 0){
        atomicAdd(&hw2s[2 * node],     s0 * di);
        atomicAdd(&hw2s[2 * node + 1], s1 * di);
    }
}

__global__ __launch_bounds__(256) void k_spmm2(const int* __restrict__ rp, const int* __restrict__ col,
                                               const float* __restrict__ dinv, const float* __restrict__ hw2s,
                                               const float* __restrict__ b2, const float* __restrict__ Wc,
                                               const float* __restrict__ bc, float* __restrict__ out, int n){
    int i = blockIdx.x * 256 + threadIdx.x;
    if (i >= n) return;
    int e0 = rp[i], e1 = rp[i + 1];
    float s0 = hw2s[2 * i], s1 = hw2s[2 * i + 1];
    for (int e = e0; e < e1; ++e){
        int s = col[e];
        s0 += hw2s[2 * s];
        s1 += hw2s[2 * s + 1];
    }
    float di = dinv[i];
    float a0 = fmaxf(di * s0 + b2[0], 0.0f);
    float a1 = fmaxf(di * s1 + b2[1], 0.0f);
    float z = a0 * Wc[0] + a1 * Wc[1] + bc[0];
    out[i] = 1.0f / (1.0f + expf(-z));
}

extern "C" void kernel_launch(void* const* d_in, const int* in_sizes, int n_in,
                              void* d_out, int out_size, void* d_ws, size_t ws_size,
                              hipStream_t stream) {
    const float* x  = (const float*)d_in[0];
    const void*  ei = d_in[1];
    const float* W1 = (const float*)d_in[2];
    const float* b1 = (const float*)d_in[3];
    const float* W2 = (const float*)d_in[4];
    const float* b2 = (const float*)d_in[5];
    const float* Wc = (const float*)d_in[6];
    const float* bc = (const float*)d_in[7];
    float* out = (float*)d_out;

    const int n = NN;
    const int E = in_sizes[1] / 2;

    char* ws = (char*)d_ws;
    size_t off = 0;
    auto alloc = [&](size_t bytes)->char*{
        off = (off + 255) & ~(size_t)255;
        char* p = ws + off; off += bytes; return p;
    };
    int*      flag    = (int*)alloc(4);
    int*      gbcnt   = (int*)alloc((size_t)NB * 4);
    int*      bbase   = (int*)alloc((size_t)(NB + 1) * 4);
    int*      bcursor = (int*)alloc((size_t)NB * 4);
    int*      rp      = (int*)alloc((size_t)(n + 1) * 4);
    float*    dinv    = (float*)alloc((size_t)n * 4);
    float*    hw2s    = (float*)alloc((size_t)n * 2 * 4);
    _Float16* Bf      = (_Float16*)alloc((size_t)192 * 128 * 2);
    int*      col     = (int*)alloc((size_t)E * 4);
    uint2*    rec     = (uint2*)alloc((size_t)E * 8);
    // xws UN-ALIASED from rec (dirty cross-XCD lines from scatter would make
    // gemm1 partial-line stores take the probe slow path). Fallback: alias.
    _Float16* xws;
    {
        size_t xws_bytes = (size_t)n * 128 * 2;
        size_t off_sep = (off + 255) & ~(size_t)255;
        if (off_sep + xws_bytes <= ws_size) xws = (_Float16*)alloc(xws_bytes);
        else                                xws = (_Float16*)rec;   // old behavior
    }
    (void)n_in; (void)out_size;

    hipMemsetAsync(gbcnt, 0, (size_t)NB * 4, stream);
    hipMemsetAsync(hw2s, 0, (size_t)n * 2 * 4, stream);
    k_detect<<<1, 256, 0, stream>>>(ei, flag, (long long)E, (long long)n);
    k_prepW<<<96, 256, 0, stream>>>(W1, Bf);

    int gN = (n + 255) / 256;
    int gT = (E + TILE - 1) / TILE;
    int gS = ((n + 3) / 4) * 8;      // (node-groups of 4) x 8 slices

    k_hist<<<256, 256, 0, stream>>>(ei, flag, gbcnt, E);
    k_scanB<<<1, NB, 0, stream>>>(gbcnt, bbase, bcursor, E);
    k_scatter<<<gT, 256, 0, stream>>>(ei, flag, bcursor, rec, E);
    k_csr<<<NB, 256, 0, stream>>>(rec, bbase, rp, col, dinv, E);
    k_gemm1<<<(n + 63) / 64, 256, 0, stream>>>(x, Bf, dinv, xws, n);
    k_spmm1<<<gS, 256, 0, stream>>>((const __half2*)xws, rp, col, dinv, b1, W2, hw2s, n);
    k_spmm2<<<gN, 256, 0, stream>>>(rp, col, dinv, hw2s, b2, Wc, bc, out, n);
}

// Round 9
// 431.410 us; speedup vs baseline: 1.0976x; 1.0976x over previous
//
#include <hip/hip_runtime.h>
#include <hip/hip_fp16.h>
#include <stdint.h>

#define NN 100000
#define NB 512
#define BUCKET 196   // ceil(NN/NB)
#define TILE 4096
#define EPT 16       // TILE / 256

typedef _Float16 f16x8 __attribute__((ext_vector_type(8)));
typedef float f32x4  __attribute__((ext_vector_type(4)));

__device__ __forceinline__ int edge_at(const void* p, int f64, long long idx){
    return f64 ? (int)((const long long*)p)[idx] : ((const int*)p)[idx];
}

// ---------- graph preprocessing ----------

__global__ void k_detect(const void* __restrict__ ep, int* flag, long long nwords, long long nn){
    __shared__ int bad;
    if (threadIdx.x == 0) bad = 0;
    __syncthreads();
    const long long* p = (const long long*)ep;
    for (long long i = threadIdx.x; i < 1024 && i < nwords; i += blockDim.x){
        long long v = p[i];
        if (v < 0 || v >= nn) atomicOr(&bad, 1);
    }
    __syncthreads();
    if (threadIdx.x == 0) flag[0] = bad ? 0 : 1;  // 1 => int64
}

__global__ __launch_bounds__(256) void k_hist(const void* __restrict__ ep, const int* __restrict__ flag,
                                              int* __restrict__ gbcnt, int E){
    __shared__ int h[NB];
    for (int i = threadIdx.x; i < NB; i += 256) h[i] = 0;
    __syncthreads();
    int f = flag[0];
    for (long long e = blockIdx.x * 256 + threadIdx.x; e < E; e += (long long)gridDim.x * 256){
        int d = edge_at(ep, f, (long long)E + e);
        atomicAdd(&h[d / BUCKET], 1);
    }
    __syncthreads();
    for (int i = threadIdx.x; i < NB; i += 256)
        if (h[i]) atomicAdd(&gbcnt[i], h[i]);
}

__global__ void k_scanB(const int* __restrict__ gbcnt, int* __restrict__ bbase,
                        int* __restrict__ bcursor, int E){
    __shared__ int sh[NB];
    int t = threadIdx.x;
    int own = gbcnt[t];
    sh[t] = own; __syncthreads();
    for (int off = 1; off < NB; off <<= 1){
        int u = (t >= off) ? sh[t - off] : 0;
        __syncthreads();
        sh[t] += u;
        __syncthreads();
    }
    int excl = sh[t] - own;
    bbase[t] = excl;
    bcursor[t] = excl;
    if (t == NB - 1) bbase[NB] = excl + own;
    (void)E;
}

__global__ __launch_bounds__(256) void k_scatter(const void* __restrict__ ep, const int* __restrict__ flag,
                                                 int* __restrict__ bcursor, uint2* __restrict__ rec, int E){
    __shared__ int h[NB];
    __shared__ int gb[NB];
    int f = flag[0];
    long long base = (long long)blockIdx.x * TILE;
    for (int i = threadIdx.x; i < NB; i += 256) h[i] = 0;
    __syncthreads();
    int s[EPT], d[EPT], r[EPT], bb[EPT];
    #pragma unroll
    for (int j = 0; j < EPT; ++j){
        long long e = base + j * 256 + threadIdx.x;
        if (e < E){
            s[j]  = edge_at(ep, f, e);
            d[j]  = edge_at(ep, f, (long long)E + e);
            bb[j] = d[j] / BUCKET;
            r[j]  = atomicAdd(&h[bb[j]], 1);
        }
    }
    __syncthreads();
    for (int i = threadIdx.x; i < NB; i += 256)
        gb[i] = h[i] ? atomicAdd(&bcursor[i], h[i]) : 0;
    __syncthreads();
    #pragma unroll
    for (int j = 0; j < EPT; ++j){
        long long e = base + j * 256 + threadIdx.x;
        if (e < E) rec[gb[bb[j]] + r[j]] = make_uint2((unsigned)s[j], (unsigned)d[j]);
    }
}

__global__ __launch_bounds__(256) void k_csr(const uint2* __restrict__ rec, const int* __restrict__ bbase,
                                             int* __restrict__ rp, int* __restrict__ col,
                                             float* __restrict__ dinv, int E){
    int b = blockIdx.x;
    int t = threadIdx.x;
    if (b == 0 && t == 0) rp[NN] = E;
    int d0 = b * BUCKET;
    if (d0 >= NN) return;
    int e0 = bbase[b], e1 = bbase[b + 1];
    __shared__ int h[BUCKET];
    __shared__ int sc[256];
    __shared__ int cur[BUCKET];
    for (int i = t; i < BUCKET; i += 256) h[i] = 0;
    __syncthreads();
    for (int e = e0 + t; e < e1; e += 256)
        atomicAdd(&h[rec[e].y - d0], 1);
    __syncthreads();
    int own = (t < BUCKET) ? h[t] : 0;
    sc[t] = own; __syncthreads();
    for (int off = 1; off < 256; off <<= 1){
        int u = (t >= off) ? sc[t - off] : 0;
        __syncthreads();
        sc[t] += u;
        __syncthreads();
    }
    int excl = sc[t] - own;
    if (t < BUCKET && d0 + t < NN){
        rp[d0 + t]   = e0 + excl;
        cur[t]       = e0 + excl;
        dinv[d0 + t] = rsqrtf((float)(own + 1));
    }
    __syncthreads();
    for (int e = e0 + t; e < e1; e += 256){
        uint2 u = rec[e];
        int p = atomicAdd(&cur[u.y - d0], 1);
        col[p] = (int)u.x;
    }
}

// ---------- GEMM1 via single-term fp16 MFMA ----------

// Pack W1 (165x128 fp32, zero-padded K to 192) into fragment-ready fp16.
__global__ __launch_bounds__(256) void k_prepW(const float* __restrict__ W1, _Float16* __restrict__ Bf){
    int q = blockIdx.x * 256 + threadIdx.x;   // 192*128 = 24576
    if (q >= 192 * 128) return;
    int k = q >> 7, c = q & 127;
    float w = (k < 165) ? W1[k * 128 + c] : 0.0f;
    int tt = k >> 5, kk = k & 31;
    int lane = ((kk >> 3) << 4) + (c & 15);
    int j = kk & 7;
    int f = c >> 4;
    int idx = (((tt * 8 + f) * 64 + lane) << 3) + j;
    Bf[idx] = (_Float16)w;
}

// C = (x @ W1) * dinv, stored fp16 in SLICE-CONTIGUOUS layout:
// xws[slice][node][16 fp16]; slice s holds cols [16s,16s+16). Each slice is a
// dense 3.2MB region -> per-XCD L2-resident in spmm1.
#define ASTRIDE 200   // fp16 elems; 400B row stride
#define CSTRIDE 136   // fp16 elems; C-tile stride (16B-aligned rows)
__global__ __launch_bounds__(256, 4) void k_gemm1(const float* __restrict__ x,
                                                  const _Float16* __restrict__ Bf16,
                                                  const float* __restrict__ dinv,
                                                  _Float16* __restrict__ xws, int n){
    __shared__ _Float16 Ah[64 * ASTRIDE];
    int t = threadIdx.x;
    int w = t >> 6, lane = t & 63;
    int i0 = blockIdx.x * 64;

    // zero ONLY K-pad columns 165..191 (no overlap with staging -> no race)
    for (int q = t; q < 64 * 27; q += 256){
        int r = q / 27, k = 165 + (q - r * 27);
        Ah[r * ASTRIDE + k] = (_Float16)0.0f;
    }

    // B fragments -> registers (12 x b128), independent of LDS staging
    f16x8 Bf[6][2];
    #pragma unroll
    for (int tt = 0; tt < 6; ++tt)
        #pragma unroll
        for (int cf = 0; cf < 2; ++cf)
            Bf[tt][cf] = *(const f16x8*)&Bf16[((tt * 8 + (w * 2 + cf)) * 64 + lane) << 3];

    // stage A tile: 64*165 = 10560 elems, flat coalesced, 7 batches of 6 indep loads
    {
        const float* src = x + (size_t)i0 * 165;
        int nElem = n - i0;
        nElem = (nElem > 64 ? 64 : nElem) * 165;
        #pragma unroll
        for (int b = 0; b < 7; ++b){
            float v[6];
            #pragma unroll
            for (int u = 0; u < 6; ++u){
                int idx = t + (b * 6 + u) * 256;
                v[u] = (idx < nElem) ? src[idx] : 0.0f;
            }
            #pragma unroll
            for (int u = 0; u < 6; ++u){
                int idx = t + (b * 6 + u) * 256;
                if (idx < 64 * 165){
                    int r = idx / 165;          // magic-mul
                    int k = idx - r * 165;
                    Ah[r * ASTRIDE + k] = (_Float16)v[u];
                }
            }
        }
    }

    f32x4 acc[4][2];
    #pragma unroll
    for (int m = 0; m < 4; ++m){ acc[m][0] = (f32x4)0.0f; acc[m][1] = (f32x4)0.0f; }

    __syncthreads();

    int rl = lane & 15, kl = (lane >> 4) * 8;
    #pragma unroll
    for (int tt = 0; tt < 6; ++tt){
        f16x8 ah[4];
        #pragma unroll
        for (int m = 0; m < 4; ++m)
            ah[m] = *(const f16x8*)&Ah[(m * 16 + rl) * ASTRIDE + tt * 32 + kl];
        #pragma unroll
        for (int m = 0; m < 4; ++m)
            #pragma unroll
            for (int cf = 0; cf < 2; ++cf)
                acc[m][cf] = __builtin_amdgcn_mfma_f32_16x16x32_f16(ah[m], Bf[tt][cf], acc[m][cf], 0, 0, 0);
    }

    // epilogue: stage C in LDS (reuse Ah), then slice-contiguous coalesced writes
    __syncthreads();           // all frag reads of Ah done
    _Float16* Cs = (_Float16*)Ah;
    #pragma unroll
    for (int m = 0; m < 4; ++m){
        int rloc = m * 16 + (lane >> 4) * 4;
        #pragma unroll
        for (int r = 0; r < 4; ++r){
            int row = i0 + rloc + r;
            float dvv = (row < n) ? dinv[row] : 0.0f;
            #pragma unroll
            for (int cf = 0; cf < 2; ++cf){
                int colg = w * 32 + cf * 16 + (lane & 15);
                Cs[(rloc + r) * CSTRIDE + colg] = (_Float16)(acc[m][cf][r] * dvv);
            }
        }
    }
    __syncthreads();
    int nrow = (i0 + 64 <= n) ? 64 : (n - i0);
    // q: s = q>>7 (slice), row = (q&127)>>1, half = q&1 ; threads 0..127 cover one
    // slice -> contiguous 2KB run per slice (full 64B lines).
    for (int q = t; q < 8 * 128; q += 256){
        int s = q >> 7, rem = q & 127, row = rem >> 1, half = rem & 1;
        if (row < nrow){
            uint4 vv = *(const uint4*)&Cs[row * CSTRIDE + s * 16 + half * 8];
            *(uint4*)&xws[((size_t)s * NN + (i0 + row)) * 16 + half * 8] = vv;
        }
    }
}

// ---------- SpMM layer 1: XCD feature-sharded gather (slice-contiguous) ----------
// Grid: (node-group x 8 slices), slice = blockIdx&7 -> round-robin XCD. Each
// XCD gathers only its own dense 3.2MB slice region (L2-resident).
__global__ __launch_bounds__(256) void k_spmm1(const __half2* __restrict__ xwh, const int* __restrict__ rp,
                                               const int* __restrict__ col, const float* __restrict__ dinv,
                                               const float* __restrict__ b1, const float* __restrict__ W2,
                                               float* __restrict__ hw2s, int n){
    int b = blockIdx.x;
    int slice = b & 7;
    int node = (b >> 3) * 4 + (threadIdx.x >> 6);
    if (node >= n) return;
    int lane = threadIdx.x & 63;
    int eg = lane >> 3, fp = lane & 7;
    int e0 = rp[node], e1 = rp[node + 1];
    float di = dinv[node];
    const __half2* base = xwh + (size_t)slice * NN * 8 + fp;   // slice region, half2 units
    __half2 zero = __float2half2_rn(0.0f);
    __half2 a = (eg == 0) ? base[(size_t)node * 8] : zero;     // self loop once
    for (int e = e0; e < e1; e += 16){
        int i1 = e + eg, i2 = e + 8 + eg;
        bool ok1 = i1 < e1, ok2 = i2 < e1;
        int c1 = ok1 ? __builtin_nontemporal_load(&col[i1]) : 0;
        int c2 = ok2 ? __builtin_nontemporal_load(&col[i2]) : 0;
        __half2 v1 = base[(size_t)c1 * 8];
        __half2 v2 = base[(size_t)c2 * 8];
        if (ok1) a = __hadd2(a, v1);
        if (ok2) a = __hadd2(a, v2);
    }
    // sum across the 8 edge-groups (lanes differing in bits 3..5)
    #pragma unroll
    for (int off = 8; off < 64; off <<= 1){
        int ai = __shfl_xor(*(int*)&a, off);
        a = __hadd2(a, *(__half2*)&ai);
    }
    float a0 = __low2float(a), a1 = __high2float(a);
    int f0 = slice * 16 + 2 * fp;
    float2 bb = *(const float2*)(b1 + f0);
    float h0 = fmaxf(di * a0 + bb.x, 0.0f);
    float h1 = fmaxf(di * a1 + bb.y, 0.0f);
    float4 wv = *(const float4*)(W2 + 2 * f0);
    float s0 = h0 * wv.x + h1 * wv.z;
    float s1 = h0 * wv.y + h1 * wv.w;
    #pragma unroll
    for (int off = 1; off < 8; off <<= 1){
        s0 += __shfl_xor(s0, off);
        s1 += __shfl_xor(s1, off);
    }
    if (lane == 0){
        atomicAdd(&hw2s[2 * node],     s0 * di);
        atomicAdd(&hw2s[2 * node + 1], s1 * di);
    }
}

__global__ __launch_bounds__(256) void k_spmm2(const int* __restrict__ rp, const int* __restrict__ col,
                                               const float* __restrict__ dinv, const float* __restrict__ hw2s,
                                               const float* __restrict__ b2, const float* __restrict__ Wc,
                                               const float* __restrict__ bc, float* __restrict__ out, int n){
    int i = blockIdx.x * 256 + threadIdx.x;
    if (i >= n) return;
    int e0 = rp[i], e1 = rp[i + 1];
    float s0 = hw2s[2 * i], s1 = hw2s[2 * i + 1];
    for (int e = e0; e < e1; ++e){
        int s = col[e];
        s0 += hw2s[2 * s];
        s1 += hw2s[2 * s + 1];
    }
    float di = dinv[i];
    float a0 = fmaxf(di * s0 + b2[0], 0.0f);
    float a1 = fmaxf(di * s1 + b2[1], 0.0f);
    float z = a0 * Wc[0] + a1 * Wc[1] + bc[0];
    out[i] = 1.0f / (1.0f + expf(-z));
}

extern "C" void kernel_launch(void* const* d_in, const int* in_sizes, int n_in,
                              void* d_out, int out_size, void* d_ws, size_t ws_size,
                              hipStream_t stream) {
    const float* x  = (const float*)d_in[0];
    const void*  ei = d_in[1];
    const float* W1 = (const float*)d_in[2];
    const float* b1 = (const float*)d_in[3];
    const float* W2 = (const float*)d_in[4];
    const float* b2 = (const float*)d_in[5];
    const float* Wc = (const float*)d_in[6];
    const float* bc = (const float*)d_in[7];
    float* out = (float*)d_out;

    const int n = NN;
    const int E = in_sizes[1] / 2;

    char* ws = (char*)d_ws;
    size_t off = 0;
    auto alloc = [&](size_t bytes)->char*{
        off = (off + 255) & ~(size_t)255;
        char* p = ws + off; off += bytes; return p;
    };
    int*      flag    = (int*)alloc(4);
    int*      gbcnt   = (int*)alloc((size_t)NB * 4);
    int*      bbase   = (int*)alloc((size_t)(NB + 1) * 4);
    int*      bcursor = (int*)alloc((size_t)NB * 4);
    int*      rp      = (int*)alloc((size_t)(n + 1) * 4);
    float*    dinv    = (float*)alloc((size_t)n * 4);
    float*    hw2s    = (float*)alloc((size_t)n * 2 * 4);
    _Float16* Bf      = (_Float16*)alloc((size_t)192 * 128 * 2);
    int*      col     = (int*)alloc((size_t)E * 4);
    uint2*    rec     = (uint2*)alloc((size_t)E * 8);
    // xws un-aliased from rec (cross-XCD dirty-line probe avoidance); fallback alias.
    _Float16* xws;
    {
        size_t xws_bytes = (size_t)n * 128 * 2;
        size_t off_sep = (off + 255) & ~(size_t)255;
        if (off_sep + xws_bytes <= ws_size) xws = (_Float16*)alloc(xws_bytes);
        else                                xws = (_Float16*)rec;   // old behavior
    }
    (void)n_in; (void)out_size;

    hipMemsetAsync(gbcnt, 0, (size_t)NB * 4, stream);
    hipMemsetAsync(hw2s, 0, (size_t)n * 2 * 4, stream);
    k_detect<<<1, 256, 0, stream>>>(ei, flag, (long long)E, (long long)n);
    k_prepW<<<96, 256, 0, stream>>>(W1, Bf);

    int gN = (n + 255) / 256;
    int gT = (E + TILE - 1) / TILE;
    int gS = ((n + 3) / 4) * 8;      // (node-groups of 4) x 8 slices

    k_hist<<<256, 256, 0, stream>>>(ei, flag, gbcnt, E);
    k_scanB<<<1, NB, 0, stream>>>(gbcnt, bbase, bcursor, E);
    k_scatter<<<gT, 256, 0, stream>>>(ei, flag, bcursor, rec, E);
    k_csr<<<NB, 256, 0, stream>>>(rec, bbase, rp, col, dinv, E);
    k_gemm1<<<(n + 63) / 64, 256, 0, stream>>>(x, Bf, dinv, xws, n);
    k_spmm1<<<gS, 256, 0, stream>>>((const __half2*)xws, rp, col, dinv, b1, W2, hw2s, n);
    k_spmm2<<<gN, 256, 0, stream>>>(rp, col, dinv, hw2s, b2, Wc, bc, out, n);
}

// Round 10
// 200.563 us; speedup vs baseline: 2.3610x; 2.1510x over previous
//
#include <hip/hip_runtime.h>
#include <hip/hip_fp16.h>
#include <stdint.h>

#define NN 100000
#define NB 512
#define BUCKET 196   // ceil(NN/NB)
#define TILE 4096
#define EPT 16       // TILE / 256

typedef _Float16 f16x8 __attribute__((ext_vector_type(8)));
typedef float f32x4  __attribute__((ext_vector_type(4)));

__device__ __forceinline__ int edge_at(const void* p, int f64, long long idx){
    return f64 ? (int)((const long long*)p)[idx] : ((const int*)p)[idx];
}

// ---------- graph preprocessing ----------

__global__ void k_detect(const void* __restrict__ ep, int* flag, long long nwords, long long nn){
    __shared__ int bad;
    if (threadIdx.x == 0) bad = 0;
    __syncthreads();
    const long long* p = (const long long*)ep;
    for (long long i = threadIdx.x; i < 1024 && i < nwords; i += blockDim.x){
        long long v = p[i];
        if (v < 0 || v >= nn) atomicOr(&bad, 1);
    }
    __syncthreads();
    if (threadIdx.x == 0) flag[0] = bad ? 0 : 1;  // 1 => int64
}

__global__ __launch_bounds__(256) void k_hist(const void* __restrict__ ep, const int* __restrict__ flag,
                                              int* __restrict__ gbcnt, int E){
    __shared__ int h[NB];
    for (int i = threadIdx.x; i < NB; i += 256) h[i] = 0;
    __syncthreads();
    int f = flag[0];
    for (long long e = blockIdx.x * 256 + threadIdx.x; e < E; e += (long long)gridDim.x * 256){
        int d = edge_at(ep, f, (long long)E + e);
        atomicAdd(&h[d / BUCKET], 1);
    }
    __syncthreads();
    for (int i = threadIdx.x; i < NB; i += 256)
        if (h[i]) atomicAdd(&gbcnt[i], h[i]);
}

__global__ void k_scanB(const int* __restrict__ gbcnt, int* __restrict__ bbase,
                        int* __restrict__ bcursor, int E){
    __shared__ int sh[NB];
    int t = threadIdx.x;
    int own = gbcnt[t];
    sh[t] = own; __syncthreads();
    for (int off = 1; off < NB; off <<= 1){
        int u = (t >= off) ? sh[t - off] : 0;
        __syncthreads();
        sh[t] += u;
        __syncthreads();
    }
    int excl = sh[t] - own;
    bbase[t] = excl;
    bcursor[t] = excl;
    if (t == NB - 1) bbase[NB] = excl + own;
    (void)E;
}

__global__ __launch_bounds__(256) void k_scatter(const void* __restrict__ ep, const int* __restrict__ flag,
                                                 int* __restrict__ bcursor, uint2* __restrict__ rec, int E){
    __shared__ int h[NB];
    __shared__ int gb[NB];
    int f = flag[0];
    long long base = (long long)blockIdx.x * TILE;
    for (int i = threadIdx.x; i < NB; i += 256) h[i] = 0;
    __syncthreads();
    int s[EPT], d[EPT], r[EPT], bb[EPT];
    #pragma unroll
    for (int j = 0; j < EPT; ++j){
        long long e = base + j * 256 + threadIdx.x;
        if (e < E){
            s[j]  = edge_at(ep, f, e);
            d[j]  = edge_at(ep, f, (long long)E + e);
            bb[j] = d[j] / BUCKET;
            r[j]  = atomicAdd(&h[bb[j]], 1);
        }
    }
    __syncthreads();
    for (int i = threadIdx.x; i < NB; i += 256)
        gb[i] = h[i] ? atomicAdd(&bcursor[i], h[i]) : 0;
    __syncthreads();
    #pragma unroll
    for (int j = 0; j < EPT; ++j){
        long long e = base + j * 256 + threadIdx.x;
        if (e < E) rec[gb[bb[j]] + r[j]] = make_uint2((unsigned)s[j], (unsigned)d[j]);
    }
}

__global__ __launch_bounds__(256) void k_csr(const uint2* __restrict__ rec, const int* __restrict__ bbase,
                                             int* __restrict__ rp, int* __restrict__ col,
                                             float* __restrict__ dinv, int E){
    int b = blockIdx.x;
    int t = threadIdx.x;
    if (b == 0 && t == 0) rp[NN] = E;
    int d0 = b * BUCKET;
    if (d0 >= NN) return;
    int e0 = bbase[b], e1 = bbase[b + 1];
    __shared__ int h[BUCKET];
    __shared__ int sc[256];
    __shared__ int cur[BUCKET];
    for (int i = t; i < BUCKET; i += 256) h[i] = 0;
    __syncthreads();
    for (int e = e0 + t; e < e1; e += 256)
        atomicAdd(&h[rec[e].y - d0], 1);
    __syncthreads();
    int own = (t < BUCKET) ? h[t] : 0;
    sc[t] = own; __syncthreads();
    for (int off = 1; off < 256; off <<= 1){
        int u = (t >= off) ? sc[t - off] : 0;
        __syncthreads();
        sc[t] += u;
        __syncthreads();
    }
    int excl = sc[t] - own;
    if (t < BUCKET && d0 + t < NN){
        rp[d0 + t]   = e0 + excl;
        cur[t]       = e0 + excl;
        dinv[d0 + t] = rsqrtf((float)(own + 1));
    }
    __syncthreads();
    for (int e = e0 + t; e < e1; e += 256){
        uint2 u = rec[e];
        int p = atomicAdd(&cur[u.y - d0], 1);
        col[p] = (int)u.x;
    }
}

// ---------- GEMM1 via single-term fp16 MFMA ----------

// Pack W1 (165x128 fp32, zero-padded K to 192) into fragment-ready fp16.
__global__ __launch_bounds__(256) void k_prepW(const float* __restrict__ W1, _Float16* __restrict__ Bf){
    int q = blockIdx.x * 256 + threadIdx.x;   // 192*128 = 24576
    if (q >= 192 * 128) return;
    int k = q >> 7, c = q & 127;
    float w = (k < 165) ? W1[k * 128 + c] : 0.0f;
    int tt = k >> 5, kk = k & 31;
    int lane = ((kk >> 3) << 4) + (c & 15);
    int j = kk & 7;
    int f = c >> 4;
    int idx = (((tt * 8 + f) * 64 + lane) << 3) + j;
    Bf[idx] = (_Float16)w;
}

// C = (x @ W1) * dinv, stored fp16 in SLICE-CONTIGUOUS layout:
// xws[slice][node][16 fp16]; slice s holds cols [16s,16s+16).
#define ASTRIDE 200   // fp16 elems; 400B row stride
#define CSTRIDE 136   // fp16 elems; C-tile stride (16B-aligned rows)
__global__ __launch_bounds__(256, 4) void k_gemm1(const float* __restrict__ x,
                                                  const _Float16* __restrict__ Bf16,
                                                  const float* __restrict__ dinv,
                                                  _Float16* __restrict__ xws, int n){
    __shared__ _Float16 Ah[64 * ASTRIDE];
    int t = threadIdx.x;
    int w = t >> 6, lane = t & 63;
    int i0 = blockIdx.x * 64;

    // zero ONLY K-pad columns 165..191
    for (int q = t; q < 64 * 27; q += 256){
        int r = q / 27, k = 165 + (q - r * 27);
        Ah[r * ASTRIDE + k] = (_Float16)0.0f;
    }

    f16x8 Bf[6][2];
    #pragma unroll
    for (int tt = 0; tt < 6; ++tt)
        #pragma unroll
        for (int cf = 0; cf < 2; ++cf)
            Bf[tt][cf] = *(const f16x8*)&Bf16[((tt * 8 + (w * 2 + cf)) * 64 + lane) << 3];

    {
        const float* src = x + (size_t)i0 * 165;
        int nElem = n - i0;
        nElem = (nElem > 64 ? 64 : nElem) * 165;
        #pragma unroll
        for (int b = 0; b < 7; ++b){
            float v[6];
            #pragma unroll
            for (int u = 0; u < 6; ++u){
                int idx = t + (b * 6 + u) * 256;
                v[u] = (idx < nElem) ? src[idx] : 0.0f;
            }
            #pragma unroll
            for (int u = 0; u < 6; ++u){
                int idx = t + (b * 6 + u) * 256;
                if (idx < 64 * 165){
                    int r = idx / 165;
                    int k = idx - r * 165;
                    Ah[r * ASTRIDE + k] = (_Float16)v[u];
                }
            }
        }
    }

    f32x4 acc[4][2];
    #pragma unroll
    for (int m = 0; m < 4; ++m){ acc[m][0] = (f32x4)0.0f; acc[m][1] = (f32x4)0.0f; }

    __syncthreads();

    int rl = lane & 15, kl = (lane >> 4) * 8;
    #pragma unroll
    for (int tt = 0; tt < 6; ++tt){
        f16x8 ah[4];
        #pragma unroll
        for (int m = 0; m < 4; ++m)
            ah[m] = *(const f16x8*)&Ah[(m * 16 + rl) * ASTRIDE + tt * 32 + kl];
        #pragma unroll
        for (int m = 0; m < 4; ++m)
            #pragma unroll
            for (int cf = 0; cf < 2; ++cf)
                acc[m][cf] = __builtin_amdgcn_mfma_f32_16x16x32_f16(ah[m], Bf[tt][cf], acc[m][cf], 0, 0, 0);
    }

    __syncthreads();           // all frag reads of Ah done
    _Float16* Cs = (_Float16*)Ah;
    #pragma unroll
    for (int m = 0; m < 4; ++m){
        int rloc = m * 16 + (lane >> 4) * 4;
        #pragma unroll
        for (int r = 0; r < 4; ++r){
            int row = i0 + rloc + r;
            float dvv = (row < n) ? dinv[row] : 0.0f;
            #pragma unroll
            for (int cf = 0; cf < 2; ++cf){
                int colg = w * 32 + cf * 16 + (lane & 15);
                Cs[(rloc + r) * CSTRIDE + colg] = (_Float16)(acc[m][cf][r] * dvv);
            }
        }
    }
    __syncthreads();
    int nrow = (i0 + 64 <= n) ? 64 : (n - i0);
    for (int q = t; q < 8 * 128; q += 256){
        int s = q >> 7, rem = q & 127, row = rem >> 1, half = rem & 1;
        if (row < nrow){
            uint4 vv = *(const uint4*)&Cs[row * CSTRIDE + s * 16 + half * 8];
            *(uint4*)&xws[((size_t)s * NN + (i0 + row)) * 16 + half * 8] = vv;
        }
    }
}

// ---------- SpMM layer 1: sliced gather, wave = 8 nodes, no atomics ----------
// slice = blockIdx&7 (XCD round-robin). Group of 8 lanes per node: lane j holds
// half2 feature-pair j of the 32B slice row. Partials to hp[slice][node][2].
__global__ __launch_bounds__(256) void k_spmm1(const __half2* __restrict__ xwh, const int* __restrict__ rp,
                                               const int* __restrict__ col, const float* __restrict__ dinv,
                                               const float* __restrict__ b1, const float* __restrict__ W2,
                                               float* __restrict__ hp, int n){
    int slice = blockIdx.x & 7;
    int wave  = threadIdx.x >> 6;
    int lane  = threadIdx.x & 63;
    int g = lane >> 3, j = lane & 7;
    int node = (blockIdx.x >> 3) * 32 + wave * 8 + g;
    bool nok = node < n;
    int e0 = 0, e1 = 0;
    if (nok){ e0 = rp[node]; e1 = rp[node + 1]; }
    float di = nok ? dinv[node] : 0.0f;
    const __half2* base = xwh + (size_t)slice * (NN * 8) + j;
    __half2 zero = __float2half2_rn(0.0f);
    __half2 a = nok ? base[(size_t)node * 8] : zero;      // self loop
    for (int e = e0; e < e1; e += 4){
        int c0 = col[e];
        int c1 = (e + 1 < e1) ? col[e + 1] : -1;
        int c2 = (e + 2 < e1) ? col[e + 2] : -1;
        int c3 = (e + 3 < e1) ? col[e + 3] : -1;
        __half2 v0 = base[(size_t)c0 * 8];
        __half2 v1 = (c1 >= 0) ? base[(size_t)c1 * 8] : zero;
        __half2 v2 = (c2 >= 0) ? base[(size_t)c2 * 8] : zero;
        __half2 v3 = (c3 >= 0) ? base[(size_t)c3 * 8] : zero;
        a = __hadd2(a, __hadd2(__hadd2(v0, v1), __hadd2(v2, v3)));
    }
    int f0 = slice * 16 + 2 * j;
    float2 bb = *(const float2*)(b1 + f0);
    float h0 = fmaxf(di * __low2float(a) + bb.x, 0.0f);
    float h1 = fmaxf(di * __high2float(a) + bb.y, 0.0f);
    float4 wv = *(const float4*)(W2 + 2 * f0);
    float s0 = h0 * wv.x + h1 * wv.z;
    float s1 = h0 * wv.y + h1 * wv.w;
    #pragma unroll
    for (int off = 1; off < 8; off <<= 1){      // reduce within 8-lane group
        s0 += __shfl_xor(s0, off);
        s1 += __shfl_xor(s1, off);
    }
    if (nok && j == 0)
        *(float2*)(hp + (size_t)slice * (NN * 2) + (size_t)node * 2) = make_float2(s0 * di, s1 * di);
}

// Fold 8 slice partials -> hw2s[node][2].
__global__ __launch_bounds__(256) void k_red(const float* __restrict__ hp, float* __restrict__ hw2s, int n){
    int i = blockIdx.x * 256 + threadIdx.x;
    if (i >= n) return;
    float s0 = 0.0f, s1 = 0.0f;
    #pragma unroll
    for (int s = 0; s < 8; ++s){
        float2 v = *(const float2*)(hp + (size_t)s * (NN * 2) + (size_t)i * 2);
        s0 += v.x; s1 += v.y;
    }
    hw2s[2 * i] = s0; hw2s[2 * i + 1] = s1;
}

// ---------- SpMM layer 2: wave = 8 nodes, lane j strides edges ----------
__global__ __launch_bounds__(256) void k_spmm2(const int* __restrict__ rp, const int* __restrict__ col,
                                               const float* __restrict__ dinv, const float* __restrict__ hw2s,
                                               const float* __restrict__ b2, const float* __restrict__ Wc,
                                               const float* __restrict__ bc, float* __restrict__ out, int n){
    int wave = threadIdx.x >> 6, lane = threadIdx.x & 63;
    int g = lane >> 3, j = lane & 7;
    int node = blockIdx.x * 32 + wave * 8 + g;
    if (node >= n) return;            // whole 8-lane group exits together
    int e0 = rp[node], e1 = rp[node + 1];
    float s0 = 0.0f, s1 = 0.0f;
    if (j == 0){ s0 = hw2s[2 * node]; s1 = hw2s[2 * node + 1]; }   // self loop
    for (int e = e0 + j; e < e1; e += 8){
        int c = col[e];
        float2 v = *(const float2*)(hw2s + 2 * c);
        s0 += v.x; s1 += v.y;
    }
    #pragma unroll
    for (int off = 1; off < 8; off <<= 1){
        s0 += __shfl_xor(s0, off);
        s1 += __shfl_xor(s1, off);
    }
    if (j == 0){
        float di = dinv[node];
        float a0 = fmaxf(di * s0 + b2[0], 0.0f);
        float a1 = fmaxf(di * s1 + b2[1], 0.0f);
        float z = a0 * Wc[0] + a1 * Wc[1] + bc[0];
        out[node] = 1.0f / (1.0f + expf(-z));
    }
}

extern "C" void kernel_launch(void* const* d_in, const int* in_sizes, int n_in,
                              void* d_out, int out_size, void* d_ws, size_t ws_size,
                              hipStream_t stream) {
    const float* x  = (const float*)d_in[0];
    const void*  ei = d_in[1];
    const float* W1 = (const float*)d_in[2];
    const float* b1 = (const float*)d_in[3];
    const float* W2 = (const float*)d_in[4];
    const float* b2 = (const float*)d_in[5];
    const float* Wc = (const float*)d_in[6];
    const float* bc = (const float*)d_in[7];
    float* out = (float*)d_out;

    const int n = NN;
    const int E = in_sizes[1] / 2;

    char* ws = (char*)d_ws;
    size_t off = 0;
    auto alloc = [&](size_t bytes)->char*{
        off = (off + 255) & ~(size_t)255;
        char* p = ws + off; off += bytes; return p;
    };
    int*      flag    = (int*)alloc(4);
    int*      gbcnt   = (int*)alloc((size_t)NB * 4);
    int*      bbase   = (int*)alloc((size_t)(NB + 1) * 4);
    int*      bcursor = (int*)alloc((size_t)NB * 4);
    int*      rp      = (int*)alloc((size_t)(n + 1) * 4);
    float*    dinv    = (float*)alloc((size_t)n * 4);
    float*    hw2s    = (float*)alloc((size_t)n * 2 * 4);
    float*    hp      = (float*)alloc((size_t)8 * n * 2 * 4);   // slice partials
    _Float16* Bf      = (_Float16*)alloc((size_t)192 * 128 * 2);
    int*      col     = (int*)alloc((size_t)E * 4);
    uint2*    rec     = (uint2*)alloc((size_t)E * 8);
    // xws un-aliased from rec (cross-XCD dirty-line probe avoidance); fallback alias.
    _Float16* xws;
    {
        size_t xws_bytes = (size_t)n * 128 * 2;
        size_t off_sep = (off + 255) & ~(size_t)255;
        if (off_sep + xws_bytes <= ws_size) xws = (_Float16*)alloc(xws_bytes);
        else                                xws = (_Float16*)rec;   // old behavior
    }
    (void)n_in; (void)out_size;

    hipMemsetAsync(gbcnt, 0, (size_t)NB * 4, stream);
    k_detect<<<1, 256, 0, stream>>>(ei, flag, (long long)E, (long long)n);
    k_prepW<<<96, 256, 0, stream>>>(W1, Bf);

    int gT = (E + TILE - 1) / TILE;
    int gS1 = ((n + 31) / 32) * 8;    // 25000: (node-chunks of 32) x 8 slices
    int gS2 = (n + 31) / 32;

    k_hist<<<256, 256, 0, stream>>>(ei, flag, gbcnt, E);
    k_scanB<<<1, NB, 0, stream>>>(gbcnt, bbase, bcursor, E);
    k_scatter<<<gT, 256, 0, stream>>>(ei, flag, bcursor, rec, E);
    k_csr<<<NB, 256, 0, stream>>>(rec, bbase, rp, col, dinv, E);
    k_gemm1<<<(n + 63) / 64, 256, 0, stream>>>(x, Bf, dinv, xws, n);
    k_spmm1<<<gS1, 256, 0, stream>>>((const __half2*)xws, rp, col, dinv, b1, W2, hp, n);
    k_red<<<(n + 255) / 256, 256, 0, stream>>>(hp, hw2s, n);
    k_spmm2<<<gS2, 256, 0, stream>>>(rp, col, dinv, hw2s, b2, Wc, bc, out, n);
}

// Round 11
// 193.737 us; speedup vs baseline: 2.4441x; 1.0352x over previous
//
#include <hip/hip_runtime.h>
#include <hip/hip_fp16.h>
#include <stdint.h>

#define NN 100000
#define NB 512
#define BUCKET 196   // ceil(NN/NB)
#define TILE 4096
#define EPT 16       // TILE / 256

typedef _Float16 f16x8 __attribute__((ext_vector_type(8)));
typedef float f32x4  __attribute__((ext_vector_type(4)));

__device__ __forceinline__ int edge_at(const void* p, int f64, long long idx){
    return f64 ? (int)((const long long*)p)[idx] : ((const int*)p)[idx];
}

// ---------- graph preprocessing ----------

__global__ void k_detect(const void* __restrict__ ep, int* flag, long long nwords, long long nn){
    __shared__ int bad;
    if (threadIdx.x == 0) bad = 0;
    __syncthreads();
    const long long* p = (const long long*)ep;
    for (long long i = threadIdx.x; i < 1024 && i < nwords; i += blockDim.x){
        long long v = p[i];
        if (v < 0 || v >= nn) atomicOr(&bad, 1);
    }
    __syncthreads();
    if (threadIdx.x == 0) flag[0] = bad ? 0 : 1;  // 1 => int64
}

__global__ __launch_bounds__(256) void k_hist(const void* __restrict__ ep, const int* __restrict__ flag,
                                              int* __restrict__ gbcnt, int E){
    __shared__ int h[NB];
    for (int i = threadIdx.x; i < NB; i += 256) h[i] = 0;
    __syncthreads();
    int f = flag[0];
    for (long long e = blockIdx.x * 256 + threadIdx.x; e < E; e += (long long)gridDim.x * 256){
        int d = edge_at(ep, f, (long long)E + e);
        atomicAdd(&h[d / BUCKET], 1);
    }
    __syncthreads();
    for (int i = threadIdx.x; i < NB; i += 256)
        if (h[i]) atomicAdd(&gbcnt[i], h[i]);
}

__global__ void k_scanB(const int* __restrict__ gbcnt, int* __restrict__ bbase,
                        int* __restrict__ bcursor, int E){
    __shared__ int sh[NB];
    int t = threadIdx.x;
    int own = gbcnt[t];
    sh[t] = own; __syncthreads();
    for (int off = 1; off < NB; off <<= 1){
        int u = (t >= off) ? sh[t - off] : 0;
        __syncthreads();
        sh[t] += u;
        __syncthreads();
    }
    int excl = sh[t] - own;
    bbase[t] = excl;
    bcursor[t] = excl;
    if (t == NB - 1) bbase[NB] = excl + own;
    (void)E;
}

__global__ __launch_bounds__(256) void k_scatter(const void* __restrict__ ep, const int* __restrict__ flag,
                                                 int* __restrict__ bcursor, uint2* __restrict__ rec, int E){
    __shared__ int h[NB];
    __shared__ int gb[NB];
    int f = flag[0];
    long long base = (long long)blockIdx.x * TILE;
    for (int i = threadIdx.x; i < NB; i += 256) h[i] = 0;
    __syncthreads();
    int s[EPT], d[EPT], r[EPT], bb[EPT];
    #pragma unroll
    for (int j = 0; j < EPT; ++j){
        long long e = base + j * 256 + threadIdx.x;
        if (e < E){
            s[j]  = edge_at(ep, f, e);
            d[j]  = edge_at(ep, f, (long long)E + e);
            bb[j] = d[j] / BUCKET;
            r[j]  = atomicAdd(&h[bb[j]], 1);
        }
    }
    __syncthreads();
    for (int i = threadIdx.x; i < NB; i += 256)
        gb[i] = h[i] ? atomicAdd(&bcursor[i], h[i]) : 0;
    __syncthreads();
    #pragma unroll
    for (int j = 0; j < EPT; ++j){
        long long e = base + j * 256 + threadIdx.x;
        if (e < E) rec[gb[bb[j]] + r[j]] = make_uint2((unsigned)s[j], (unsigned)d[j]);
    }
}

__global__ __launch_bounds__(256) void k_csr(const uint2* __restrict__ rec, const int* __restrict__ bbase,
                                             int* __restrict__ rp, int* __restrict__ col,
                                             float* __restrict__ dinv, int E){
    int b = blockIdx.x;
    int t = threadIdx.x;
    if (b == 0 && t == 0) rp[NN] = E;
    int d0 = b * BUCKET;
    if (d0 >= NN) return;
    int e0 = bbase[b], e1 = bbase[b + 1];
    __shared__ int h[BUCKET];
    __shared__ int sc[256];
    __shared__ int cur[BUCKET];
    for (int i = t; i < BUCKET; i += 256) h[i] = 0;
    __syncthreads();
    for (int e = e0 + t; e < e1; e += 256)
        atomicAdd(&h[rec[e].y - d0], 1);
    __syncthreads();
    int own = (t < BUCKET) ? h[t] : 0;
    sc[t] = own; __syncthreads();
    for (int off = 1; off < 256; off <<= 1){
        int u = (t >= off) ? sc[t - off] : 0;
        __syncthreads();
        sc[t] += u;
        __syncthreads();
    }
    int excl = sc[t] - own;
    if (t < BUCKET && d0 + t < NN){
        rp[d0 + t]   = e0 + excl;
        cur[t]       = e0 + excl;
        dinv[d0 + t] = rsqrtf((float)(own + 1));
    }
    __syncthreads();
    for (int e = e0 + t; e < e1; e += 256){
        uint2 u = rec[e];
        int p = atomicAdd(&cur[u.y - d0], 1);
        col[p] = (int)u.x;
    }
}

// ---------- GEMM1 via single-term fp16 MFMA ----------

// Pack W1 (165x128 fp32, zero-padded K to 192) into fragment-ready fp16.
__global__ __launch_bounds__(256) void k_prepW(const float* __restrict__ W1, _Float16* __restrict__ Bf){
    int q = blockIdx.x * 256 + threadIdx.x;   // 192*128 = 24576
    if (q >= 192 * 128) return;
    int k = q >> 7, c = q & 127;
    float w = (k < 165) ? W1[k * 128 + c] : 0.0f;
    int tt = k >> 5, kk = k & 31;
    int lane = ((kk >> 3) << 4) + (c & 15);
    int j = kk & 7;
    int f = c >> 4;
    int idx = (((tt * 8 + f) * 64 + lane) << 3) + j;
    Bf[idx] = (_Float16)w;
}

// C = (x @ W1) * dinv, stored fp16 in SLICE-CONTIGUOUS layout:
// xws[slice][node][16 fp16]; slice s holds cols [16s,16s+16).
#define ASTRIDE 200   // fp16 elems; 400B row stride
#define CSTRIDE 136   // fp16 elems; C-tile stride (16B-aligned rows)
__global__ __launch_bounds__(256, 4) void k_gemm1(const float* __restrict__ x,
                                                  const _Float16* __restrict__ Bf16,
                                                  const float* __restrict__ dinv,
                                                  _Float16* __restrict__ xws, int n){
    __shared__ _Float16 Ah[64 * ASTRIDE];
    int t = threadIdx.x;
    int w = t >> 6, lane = t & 63;
    int i0 = blockIdx.x * 64;

    // zero ONLY K-pad columns 165..191
    for (int q = t; q < 64 * 27; q += 256){
        int r = q / 27, k = 165 + (q - r * 27);
        Ah[r * ASTRIDE + k] = (_Float16)0.0f;
    }

    f16x8 Bf[6][2];
    #pragma unroll
    for (int tt = 0; tt < 6; ++tt)
        #pragma unroll
        for (int cf = 0; cf < 2; ++cf)
            Bf[tt][cf] = *(const f16x8*)&Bf16[((tt * 8 + (w * 2 + cf)) * 64 + lane) << 3];

    {
        const float* src = x + (size_t)i0 * 165;
        int nElem = n - i0;
        nElem = (nElem > 64 ? 64 : nElem) * 165;
        #pragma unroll
        for (int b = 0; b < 7; ++b){
            float v[6];
            #pragma unroll
            for (int u = 0; u < 6; ++u){
                int idx = t + (b * 6 + u) * 256;
                v[u] = (idx < nElem) ? src[idx] : 0.0f;
            }
            #pragma unroll
            for (int u = 0; u < 6; ++u){
                int idx = t + (b * 6 + u) * 256;
                if (idx < 64 * 165){
                    int r = idx / 165;
                    int k = idx - r * 165;
                    Ah[r * ASTRIDE + k] = (_Float16)v[u];
                }
            }
        }
    }

    f32x4 acc[4][2];
    #pragma unroll
    for (int m = 0; m < 4; ++m){ acc[m][0] = (f32x4)0.0f; acc[m][1] = (f32x4)0.0f; }

    __syncthreads();

    int rl = lane & 15, kl = (lane >> 4) * 8;
    #pragma unroll
    for (int tt = 0; tt < 6; ++tt){
        f16x8 ah[4];
        #pragma unroll
        for (int m = 0; m < 4; ++m)
            ah[m] = *(const f16x8*)&Ah[(m * 16 + rl) * ASTRIDE + tt * 32 + kl];
        #pragma unroll
        for (int m = 0; m < 4; ++m)
            #pragma unroll
            for (int cf = 0; cf < 2; ++cf)
                acc[m][cf] = __builtin_amdgcn_mfma_f32_16x16x32_f16(ah[m], Bf[tt][cf], acc[m][cf], 0, 0, 0);
    }

    __syncthreads();           // all frag reads of Ah done
    _Float16* Cs = (_Float16*)Ah;
    #pragma unroll
    for (int m = 0; m < 4; ++m){
        int rloc = m * 16 + (lane >> 4) * 4;
        #pragma unroll
        for (int r = 0; r < 4; ++r){
            int row = i0 + rloc + r;
            float dvv = (row < n) ? dinv[row] : 0.0f;
            #pragma unroll
            for (int cf = 0; cf < 2; ++cf){
                int colg = w * 32 + cf * 16 + (lane & 15);
                Cs[(rloc + r) * CSTRIDE + colg] = (_Float16)(acc[m][cf][r] * dvv);
            }
        }
    }
    __syncthreads();
    int nrow = (i0 + 64 <= n) ? 64 : (n - i0);
    for (int q = t; q < 8 * 128; q += 256){
        int s = q >> 7, rem = q & 127, row = rem >> 1, half = rem & 1;
        if (row < nrow){
            uint4 vv = *(const uint4*)&Cs[row * CSTRIDE + s * 16 + half * 8];
            *(uint4*)&xws[((size_t)s * NN + (i0 + row)) * 16 + half * 8] = vv;
        }
    }
}

// ---------- SpMM layer 1: sliced gather, 8-edge chunks, shuffle-broadcast col ----------
// slice = blockIdx&7 (XCD round-robin); group of 8 lanes per node; lane j holds
// feature-pair j. col read lane-parallel (1 VMEM per 8 edges), broadcast via __shfl.
__global__ __launch_bounds__(256) void k_spmm1(const __half2* __restrict__ xwh, const int* __restrict__ rp,
                                               const int* __restrict__ col, const float* __restrict__ dinv,
                                               const float* __restrict__ b1, const float* __restrict__ W2,
                                               float* __restrict__ hp, int n){
    int slice = blockIdx.x & 7;
    int wave  = threadIdx.x >> 6;
    int lane  = threadIdx.x & 63;
    int g = lane >> 3, j = lane & 7;
    int node = (blockIdx.x >> 3) * 32 + wave * 8 + g;
    bool nok = node < n;
    int e0 = 0, e1 = 0;
    if (nok){ e0 = rp[node]; e1 = rp[node + 1]; }
    float di = nok ? dinv[node] : 0.0f;
    const char* sb = (const char*)xwh + (size_t)slice * (NN * 32);   // uniform SGPR base
    int joff = j << 2;
    int lbase = lane & 0x38;                                         // group base lane
    __half2 zero = __float2half2_rn(0.0f);
    __half2 a = nok ? *(const __half2*)(sb + (((unsigned)node << 5) + joff)) : zero;  // self loop
    int e = e0;
    // full 8-edge chunks: 1 col VMEM + 8 gathers, no guards
    for (; e + 8 <= e1; e += 8){
        int ce = col[e + j];
        #pragma unroll
        for (int k = 0; k < 8; ++k){
            int ck = __shfl(ce, lbase + k);
            __half2 v = *(const __half2*)(sb + (((unsigned)ck << 5) + joff));
            a = __hadd2(a, v);
        }
    }
    // tail chunk (0..7 edges), guarded
    int rem = e1 - e;
    if (rem > 0){
        int ce = (j < rem) ? col[e + j] : 0;
        #pragma unroll
        for (int k = 0; k < 8; ++k){
            int ck = __shfl(ce, lbase + k);
            __half2 v = *(const __half2*)(sb + (((unsigned)ck << 5) + joff));
            if (k < rem) a = __hadd2(a, v);
        }
    }
    int f0 = slice * 16 + 2 * j;
    float2 bb = *(const float2*)(b1 + f0);
    float h0 = fmaxf(di * __low2float(a) + bb.x, 0.0f);
    float h1 = fmaxf(di * __high2float(a) + bb.y, 0.0f);
    float4 wv = *(const float4*)(W2 + 2 * f0);
    float s0 = h0 * wv.x + h1 * wv.z;
    float s1 = h0 * wv.y + h1 * wv.w;
    #pragma unroll
    for (int off = 1; off < 8; off <<= 1){      // reduce within 8-lane group
        s0 += __shfl_xor(s0, off);
        s1 += __shfl_xor(s1, off);
    }
    if (nok && j == 0)
        *(float2*)(hp + (size_t)slice * (NN * 2) + (size_t)node * 2) = make_float2(s0 * di, s1 * di);
}

// Fold 8 slice partials -> hw2s[node][2].
__global__ __launch_bounds__(256) void k_red(const float* __restrict__ hp, float* __restrict__ hw2s, int n){
    int i = blockIdx.x * 256 + threadIdx.x;
    if (i >= n) return;
    float s0 = 0.0f, s1 = 0.0f;
    #pragma unroll
    for (int s = 0; s < 8; ++s){
        float2 v = *(const float2*)(hp + (size_t)s * (NN * 2) + (size_t)i * 2);
        s0 += v.x; s1 += v.y;
    }
    hw2s[2 * i] = s0; hw2s[2 * i + 1] = s1;
}

// ---------- SpMM layer 2: wave = 8 nodes, lane j strides edges ----------
__global__ __launch_bounds__(256) void k_spmm2(const int* __restrict__ rp, const int* __restrict__ col,
                                               const float* __restrict__ dinv, const float* __restrict__ hw2s,
                                               const float* __restrict__ b2, const float* __restrict__ Wc,
                                               const float* __restrict__ bc, float* __restrict__ out, int n){
    int wave = threadIdx.x >> 6, lane = threadIdx.x & 63;
    int g = lane >> 3, j = lane & 7;
    int node = blockIdx.x * 32 + wave * 8 + g;
    if (node >= n) return;            // whole 8-lane group exits together
    int e0 = rp[node], e1 = rp[node + 1];
    float s0 = 0.0f, s1 = 0.0f;
    if (j == 0){ s0 = hw2s[2 * node]; s1 = hw2s[2 * node + 1]; }   // self loop
    for (int e = e0 + j; e < e1; e += 8){
        int c = col[e];
        float2 v = *(const float2*)(hw2s + 2 * c);
        s0 += v.x; s1 += v.y;
    }
    #pragma unroll
    for (int off = 1; off < 8; off <<= 1){
        s0 += __shfl_xor(s0, off);
        s1 += __shfl_xor(s1, off);
    }
    if (j == 0){
        float di = dinv[node];
        float a0 = fmaxf(di * s0 + b2[0], 0.0f);
        float a1 = fmaxf(di * s1 + b2[1], 0.0f);
        float z = a0 * Wc[0] + a1 * Wc[1] + bc[0];
        out[node] = 1.0f / (1.0f + expf(-z));
    }
}

extern "C" void kernel_launch(void* const* d_in, const int* in_sizes, int n_in,
                              void* d_out, int out_size, void* d_ws, size_t ws_size,
                              hipStream_t stream) {
    const float* x  = (const float*)d_in[0];
    const void*  ei = d_in[1];
    const float* W1 = (const float*)d_in[2];
    const float* b1 = (const float*)d_in[3];
    const float* W2 = (const float*)d_in[4];
    const float* b2 = (const float*)d_in[5];
    const float* Wc = (const float*)d_in[6];
    const float* bc = (const float*)d_in[7];
    float* out = (float*)d_out;

    const int n = NN;
    const int E = in_sizes[1] / 2;

    char* ws = (char*)d_ws;
    size_t off = 0;
    auto alloc = [&](size_t bytes)->char*{
        off = (off + 255) & ~(size_t)255;
        char* p = ws + off; off += bytes; return p;
    };
    int*      flag    = (int*)alloc(4);
    int*      gbcnt   = (int*)alloc((size_t)NB * 4);
    int*      bbase   = (int*)alloc((size_t)(NB + 1) * 4);
    int*      bcursor = (int*)alloc((size_t)NB * 4);
    int*      rp      = (int*)alloc((size_t)(n + 1) * 4);
    float*    dinv    = (float*)alloc((size_t)n * 4);
    float*    hw2s    = (float*)alloc((size_t)n * 2 * 4);
    float*    hp      = (float*)alloc((size_t)8 * n * 2 * 4);   // slice partials
    _Float16* Bf      = (_Float16*)alloc((size_t)192 * 128 * 2);
    int*      col     = (int*)alloc((size_t)E * 4);
    uint2*    rec     = (uint2*)alloc((size_t)E * 8);
    // xws un-aliased from rec (cross-XCD dirty-line probe avoidance); fallback alias.
    _Float16* xws;
    {
        size_t xws_bytes = (size_t)n * 128 * 2;
        size_t off_sep = (off + 255) & ~(size_t)255;
        if (off_sep + xws_bytes <= ws_size) xws = (_Float16*)alloc(xws_bytes);
        else                                xws = (_Float16*)rec;   // old behavior
    }
    (void)n_in; (void)out_size;

    hipMemsetAsync(gbcnt, 0, (size_t)NB * 4, stream);
    k_detect<<<1, 256, 0, stream>>>(ei, flag, (long long)E, (long long)n);
    k_prepW<<<96, 256, 0, stream>>>(W1, Bf);

    int gT = (E + TILE - 1) / TILE;
    int gS1 = ((n + 31) / 32) * 8;    // (node-chunks of 32) x 8 slices
    int gS2 = (n + 31) / 32;

    k_hist<<<256, 256, 0, stream>>>(ei, flag, gbcnt, E);
    k_scanB<<<1, NB, 0, stream>>>(gbcnt, bbase, bcursor, E);
    k_scatter<<<gT, 256, 0, stream>>>(ei, flag, bcursor, rec, E);
    k_csr<<<NB, 256, 0, stream>>>(rec, bbase, rp, col, dinv, E);
    k_gemm1<<<(n + 63) / 64, 256, 0, stream>>>(x, Bf, dinv, xws, n);
    k_spmm1<<<gS1, 256, 0, stream>>>((const __half2*)xws, rp, col, dinv, b1, W2, hp, n);
    k_red<<<(n + 255) / 256, 256, 0, stream>>>(hp, hw2s, n);
    k_spmm2<<<gS2, 256, 0, stream>>>(rp, col, dinv, hw2s, b2, Wc, bc, out, n);
}

// Round 12
// 189.130 us; speedup vs baseline: 2.5037x; 1.0244x over previous
//
#include <hip/hip_runtime.h>
#include <hip/hip_fp16.h>
#include <stdint.h>

#define NN 100000
#define NB 512
#define BUCKET 196   // ceil(NN/NB)
#define TILE 4096
#define EPT 16       // TILE / 256

typedef _Float16 f16x8 __attribute__((ext_vector_type(8)));
typedef float f32x4  __attribute__((ext_vector_type(4)));

__device__ __forceinline__ int edge_at(const void* p, int f64, long long idx){
    return f64 ? (int)((const long long*)p)[idx] : ((const int*)p)[idx];
}

// ---------- graph preprocessing ----------

__global__ void k_detect(const void* __restrict__ ep, int* flag, long long nwords, long long nn){
    __shared__ int bad;
    if (threadIdx.x == 0) bad = 0;
    __syncthreads();
    const long long* p = (const long long*)ep;
    for (long long i = threadIdx.x; i < 1024 && i < nwords; i += blockDim.x){
        long long v = p[i];
        if (v < 0 || v >= nn) atomicOr(&bad, 1);
    }
    __syncthreads();
    if (threadIdx.x == 0) flag[0] = bad ? 0 : 1;  // 1 => int64
}

__global__ __launch_bounds__(256) void k_hist(const void* __restrict__ ep, const int* __restrict__ flag,
                                              int* __restrict__ gbcnt, int E){
    __shared__ int h[NB];
    for (int i = threadIdx.x; i < NB; i += 256) h[i] = 0;
    __syncthreads();
    int f = flag[0];
    for (long long e = blockIdx.x * 256 + threadIdx.x; e < E; e += (long long)gridDim.x * 256){
        int d = edge_at(ep, f, (long long)E + e);
        atomicAdd(&h[d / BUCKET], 1);
    }
    __syncthreads();
    for (int i = threadIdx.x; i < NB; i += 256)
        if (h[i]) atomicAdd(&gbcnt[i], h[i]);
}

__global__ void k_scanB(const int* __restrict__ gbcnt, int* __restrict__ bbase,
                        int* __restrict__ bcursor, int E){
    __shared__ int sh[NB];
    int t = threadIdx.x;
    int own = gbcnt[t];
    sh[t] = own; __syncthreads();
    for (int off = 1; off < NB; off <<= 1){
        int u = (t >= off) ? sh[t - off] : 0;
        __syncthreads();
        sh[t] += u;
        __syncthreads();
    }
    int excl = sh[t] - own;
    bbase[t] = excl;
    bcursor[t] = excl;
    if (t == NB - 1) bbase[NB] = excl + own;
    (void)E;
}

// LDS-staged scatter: rank -> compact into LDS -> per-bucket coalesced flush.
__global__ __launch_bounds__(256) void k_scatter(const void* __restrict__ ep, const int* __restrict__ flag,
                                                 int* __restrict__ bcursor, uint2* __restrict__ rec, int E){
    __shared__ int h[NB];
    __shared__ int gb[NB];
    __shared__ int lo[NB];
    __shared__ int sc[256];
    __shared__ uint2 staged[TILE];
    __shared__ int sdst[TILE];
    int t = threadIdx.x;
    int f = flag[0];
    long long base = (long long)blockIdx.x * TILE;
    for (int i = t; i < NB; i += 256) h[i] = 0;
    __syncthreads();
    int s[EPT], d[EPT], r[EPT], bb[EPT];
    #pragma unroll
    for (int j = 0; j < EPT; ++j){
        long long e = base + j * 256 + t;
        if (e < E){
            s[j]  = edge_at(ep, f, e);
            d[j]  = edge_at(ep, f, (long long)E + e);
            bb[j] = d[j] / BUCKET;
            r[j]  = atomicAdd(&h[bb[j]], 1);
        }
    }
    __syncthreads();
    // exclusive scan of h[512] -> lo[512] (each thread owns 2 buckets)
    {
        int b0 = 2 * t, b1i = b0 + 1;
        int own = h[b0] + h[b1i];
        sc[t] = own; __syncthreads();
        for (int off = 1; off < 256; off <<= 1){
            int u = (t >= off) ? sc[t - off] : 0;
            __syncthreads();
            sc[t] += u;
            __syncthreads();
        }
        int excl = sc[t] - own;
        lo[b0]  = excl;
        lo[b1i] = excl + h[b0];
    }
    for (int i = t; i < NB; i += 256)
        gb[i] = h[i] ? atomicAdd(&bcursor[i], h[i]) : 0;
    __syncthreads();
    #pragma unroll
    for (int j = 0; j < EPT; ++j){
        long long e = base + j * 256 + t;
        if (e < E){
            int slot = lo[bb[j]] + r[j];
            staged[slot] = make_uint2((unsigned)s[j], (unsigned)d[j]);
            sdst[slot]   = gb[bb[j]] + r[j];
        }
    }
    __syncthreads();
    int cnt = (E - base < TILE) ? (int)(E - base) : TILE;
    for (int q = t; q < cnt; q += 256)
        rec[sdst[q]] = staged[q];
}

__global__ __launch_bounds__(256) void k_csr(const uint2* __restrict__ rec, const int* __restrict__ bbase,
                                             int* __restrict__ rp, int* __restrict__ col,
                                             float* __restrict__ dinv, int E){
    int b = blockIdx.x;
    int t = threadIdx.x;
    if (b == 0 && t == 0) rp[NN] = E;
    int d0 = b * BUCKET;
    if (d0 >= NN) return;
    int e0 = bbase[b], e1 = bbase[b + 1];
    __shared__ int h[BUCKET];
    __shared__ int sc[256];
    __shared__ int cur[BUCKET];
    for (int i = t; i < BUCKET; i += 256) h[i] = 0;
    __syncthreads();
    for (int e = e0 + t; e < e1; e += 256)
        atomicAdd(&h[rec[e].y - d0], 1);
    __syncthreads();
    int own = (t < BUCKET) ? h[t] : 0;
    sc[t] = own; __syncthreads();
    for (int off = 1; off < 256; off <<= 1){
        int u = (t >= off) ? sc[t - off] : 0;
        __syncthreads();
        sc[t] += u;
        __syncthreads();
    }
    int excl = sc[t] - own;
    if (t < BUCKET && d0 + t < NN){
        rp[d0 + t]   = e0 + excl;
        cur[t]       = e0 + excl;
        dinv[d0 + t] = rsqrtf((float)(own + 1));
    }
    __syncthreads();
    for (int e = e0 + t; e < e1; e += 256){
        uint2 u = rec[e];
        int p = atomicAdd(&cur[u.y - d0], 1);
        col[p] = (int)u.x;
    }
}

// ---------- GEMM1 via single-term fp16 MFMA ----------

__global__ __launch_bounds__(256) void k_prepW(const float* __restrict__ W1, _Float16* __restrict__ Bf){
    int q = blockIdx.x * 256 + threadIdx.x;   // 192*128 = 24576
    if (q >= 192 * 128) return;
    int k = q >> 7, c = q & 127;
    float w = (k < 165) ? W1[k * 128 + c] : 0.0f;
    int tt = k >> 5, kk = k & 31;
    int lane = ((kk >> 3) << 4) + (c & 15);
    int j = kk & 7;
    int f = c >> 4;
    int idx = (((tt * 8 + f) * 64 + lane) << 3) + j;
    Bf[idx] = (_Float16)w;
}

// C = (x @ W1) * dinv, stored fp16 ROW-MAJOR [node][128], full-line epilogue.
#define ASTRIDE 200   // fp16 elems; 400B row stride
#define CSTRIDE 136   // fp16 elems; C-tile stride (16B-aligned rows)
__global__ __launch_bounds__(256, 4) void k_gemm1(const float* __restrict__ x,
                                                  const _Float16* __restrict__ Bf16,
                                                  const float* __restrict__ dinv,
                                                  _Float16* __restrict__ xws, int n){
    __shared__ _Float16 Ah[64 * ASTRIDE];
    int t = threadIdx.x;
    int w = t >> 6, lane = t & 63;
    int i0 = blockIdx.x * 64;

    // zero ONLY K-pad columns 165..191
    for (int q = t; q < 64 * 27; q += 256){
        int r = q / 27, k = 165 + (q - r * 27);
        Ah[r * ASTRIDE + k] = (_Float16)0.0f;
    }

    f16x8 Bf[6][2];
    #pragma unroll
    for (int tt = 0; tt < 6; ++tt)
        #pragma unroll
        for (int cf = 0; cf < 2; ++cf)
            Bf[tt][cf] = *(const f16x8*)&Bf16[((tt * 8 + (w * 2 + cf)) * 64 + lane) << 3];

    {
        const float* src = x + (size_t)i0 * 165;
        int nElem = n - i0;
        nElem = (nElem > 64 ? 64 : nElem) * 165;
        #pragma unroll
        for (int b = 0; b < 7; ++b){
            float v[6];
            #pragma unroll
            for (int u = 0; u < 6; ++u){
                int idx = t + (b * 6 + u) * 256;
                v[u] = (idx < nElem) ? src[idx] : 0.0f;
            }
            #pragma unroll
            for (int u = 0; u < 6; ++u){
                int idx = t + (b * 6 + u) * 256;
                if (idx < 64 * 165){
                    int r = idx / 165;
                    int k = idx - r * 165;
                    Ah[r * ASTRIDE + k] = (_Float16)v[u];
                }
            }
        }
    }

    f32x4 acc[4][2];
    #pragma unroll
    for (int m = 0; m < 4; ++m){ acc[m][0] = (f32x4)0.0f; acc[m][1] = (f32x4)0.0f; }

    __syncthreads();

    int rl = lane & 15, kl = (lane >> 4) * 8;
    #pragma unroll
    for (int tt = 0; tt < 6; ++tt){
        f16x8 ah[4];
        #pragma unroll
        for (int m = 0; m < 4; ++m)
            ah[m] = *(const f16x8*)&Ah[(m * 16 + rl) * ASTRIDE + tt * 32 + kl];
        #pragma unroll
        for (int m = 0; m < 4; ++m)
            #pragma unroll
            for (int cf = 0; cf < 2; ++cf)
                acc[m][cf] = __builtin_amdgcn_mfma_f32_16x16x32_f16(ah[m], Bf[tt][cf], acc[m][cf], 0, 0, 0);
    }

    __syncthreads();           // all frag reads of Ah done
    _Float16* Cs = (_Float16*)Ah;
    #pragma unroll
    for (int m = 0; m < 4; ++m){
        int rloc = m * 16 + (lane >> 4) * 4;
        #pragma unroll
        for (int r = 0; r < 4; ++r){
            int row = i0 + rloc + r;
            float dvv = (row < n) ? dinv[row] : 0.0f;
            #pragma unroll
            for (int cf = 0; cf < 2; ++cf){
                int colg = w * 32 + cf * 16 + (lane & 15);
                Cs[(rloc + r) * CSTRIDE + colg] = (_Float16)(acc[m][cf][r] * dvv);
            }
        }
    }
    __syncthreads();
    int nrow = (i0 + 64 <= n) ? 64 : (n - i0);
    for (int q = t; q < nrow * 16; q += 256){   // 16 uint4 = 128 fp16 per row
        int row = q >> 4, cw = q & 15;
        uint4 vv = *(const uint4*)&Cs[row * CSTRIDE + cw * 8];
        *(uint4*)&xws[((size_t)(i0 + row)) * 128 + cw * 8] = vv;
    }
}

// ---------- SpMM layer 1: 2 nodes/wave, full-row gathers, 16 loads in flight ----------
__global__ __launch_bounds__(256) void k_spmm1(const __half2* __restrict__ xwh, const int* __restrict__ rp,
                                               const int* __restrict__ col, const float* __restrict__ dinv,
                                               const float* __restrict__ b1, const float* __restrict__ W2,
                                               float* __restrict__ hw2s, int n){
    int wp = (blockIdx.x * 256 + threadIdx.x) >> 6;   // wave id = node pair
    int lane = threadIdx.x & 63;
    int iA = wp * 2;
    if (iA >= n) return;
    int iB = iA + 1;
    bool hasB = iB < n;
    int e0A = rp[iA], e1A = rp[iA + 1];
    int e1B = hasB ? rp[iB + 1] : e1A;
    int e0B = e1A;
    float diA = dinv[iA];
    float diB = hasB ? dinv[iB] : 0.0f;
    __half2 aA = xwh[(size_t)iA * 64 + lane];                                   // self loop A
    __half2 aB = hasB ? xwh[(size_t)iB * 64 + lane] : __float2half2_rn(0.0f);   // self loop B
    int eA = e0A, eB = e0B;
    while (eA < e1A || eB < e1B){
        int mA = e1A - eA; mA = mA > 8 ? 8 : mA;      // may be <= 0
        int mB = e1B - eB; mB = mB > 8 ? 8 : mB;
        int cA = (lane < mA) ? col[eA + lane] : 0;
        int cB = (lane < mB) ? col[eB + lane] : 0;
        #pragma unroll
        for (int k = 0; k < 8; ++k){
            int sA = __builtin_amdgcn_readlane(cA, k);
            int sB = __builtin_amdgcn_readlane(cB, k);
            __half2 vA = xwh[(size_t)sA * 64 + lane];
            __half2 vB = xwh[(size_t)sB * 64 + lane];
            if (k < mA) aA = __hadd2(aA, vA);
            if (k < mB) aB = __hadd2(aB, vB);
        }
        eA += 8; eB += 8;
    }
    int f0 = 2 * lane;
    float2 bv = *(const float2*)(b1 + f0);
    float4 wv = *(const float4*)(W2 + 2 * f0);
    float h0 = fmaxf(diA * __low2float(aA) + bv.x, 0.0f);
    float h1 = fmaxf(diA * __high2float(aA) + bv.y, 0.0f);
    float s0A = h0 * wv.x + h1 * wv.z;
    float s1A = h0 * wv.y + h1 * wv.w;
    h0 = fmaxf(diB * __low2float(aB) + bv.x, 0.0f);
    h1 = fmaxf(diB * __high2float(aB) + bv.y, 0.0f);
    float s0B = h0 * wv.x + h1 * wv.z;
    float s1B = h0 * wv.y + h1 * wv.w;
    #pragma unroll
    for (int off = 32; off > 0; off >>= 1){
        s0A += __shfl_xor(s0A, off);
        s1A += __shfl_xor(s1A, off);
        s0B += __shfl_xor(s0B, off);
        s1B += __shfl_xor(s1B, off);
    }
    if (lane == 0){
        if (hasB)
            *(float4*)(hw2s + 2 * iA) = make_float4(s0A * diA, s1A * diA, s0B * diB, s1B * diB);
        else
            *(float2*)(hw2s + 2 * iA) = make_float2(s0A * diA, s1A * diA);
    }
}

// ---------- SpMM layer 2: wave = 8 nodes, lane j strides edges ----------
__global__ __launch_bounds__(256) void k_spmm2(const int* __restrict__ rp, const int* __restrict__ col,
                                               const float* __restrict__ dinv, const float* __restrict__ hw2s,
                                               const float* __restrict__ b2, const float* __restrict__ Wc,
                                               const float* __restrict__ bc, float* __restrict__ out, int n){
    int wave = threadIdx.x >> 6, lane = threadIdx.x & 63;
    int g = lane >> 3, j = lane & 7;
    int node = blockIdx.x * 32 + wave * 8 + g;
    if (node >= n) return;
    int e0 = rp[node], e1 = rp[node + 1];
    float s0 = 0.0f, s1 = 0.0f;
    if (j == 0){ s0 = hw2s[2 * node]; s1 = hw2s[2 * node + 1]; }   // self loop
    for (int e = e0 + j; e < e1; e += 8){
        int c = col[e];
        float2 v = *(const float2*)(hw2s + 2 * c);
        s0 += v.x; s1 += v.y;
    }
    #pragma unroll
    for (int off = 1; off < 8; off <<= 1){
        s0 += __shfl_xor(s0, off);
        s1 += __shfl_xor(s1, off);
    }
    if (j == 0){
        float di = dinv[node];
        float a0 = fmaxf(di * s0 + b2[0], 0.0f);
        float a1 = fmaxf(di * s1 + b2[1], 0.0f);
        float z = a0 * Wc[0] + a1 * Wc[1] + bc[0];
        out[node] = 1.0f / (1.0f + expf(-z));
    }
}

extern "C" void kernel_launch(void* const* d_in, const int* in_sizes, int n_in,
                              void* d_out, int out_size, void* d_ws, size_t ws_size,
                              hipStream_t stream) {
    const float* x  = (const float*)d_in[0];
    const void*  ei = d_in[1];
    const float* W1 = (const float*)d_in[2];
    const float* b1 = (const float*)d_in[3];
    const float* W2 = (const float*)d_in[4];
    const float* b2 = (const float*)d_in[5];
    const float* Wc = (const float*)d_in[6];
    const float* bc = (const float*)d_in[7];
    float* out = (float*)d_out;

    const int n = NN;
    const int E = in_sizes[1] / 2;

    char* ws = (char*)d_ws;
    size_t off = 0;
    auto alloc = [&](size_t bytes)->char*{
        off = (off + 255) & ~(size_t)255;
        char* p = ws + off; off += bytes; return p;
    };
    int*      flag    = (int*)alloc(4);
    int*      gbcnt   = (int*)alloc((size_t)NB * 4);
    int*      bbase   = (int*)alloc((size_t)(NB + 1) * 4);
    int*      bcursor = (int*)alloc((size_t)NB * 4);
    int*      rp      = (int*)alloc((size_t)(n + 1) * 4);
    float*    dinv    = (float*)alloc((size_t)n * 4);
    float*    hw2s    = (float*)alloc((size_t)n * 2 * 4);
    _Float16* Bf      = (_Float16*)alloc((size_t)192 * 128 * 2);
    int*      col     = (int*)alloc((size_t)E * 4);
    uint2*    rec     = (uint2*)alloc((size_t)E * 8);
    // xws un-aliased from rec (cross-XCD dirty-line probe avoidance); fallback alias.
    _Float16* xws;
    {
        size_t xws_bytes = (size_t)n * 128 * 2;
        size_t off_sep = (off + 255) & ~(size_t)255;
        if (off_sep + xws_bytes <= ws_size) xws = (_Float16*)alloc(xws_bytes);
        else                                xws = (_Float16*)rec;   // old behavior
    }
    (void)n_in; (void)out_size;

    hipMemsetAsync(gbcnt, 0, (size_t)NB * 4, stream);
    k_detect<<<1, 256, 0, stream>>>(ei, flag, (long long)E, (long long)n);
    k_prepW<<<96, 256, 0, stream>>>(W1, Bf);

    int gT = (E + TILE - 1) / TILE;
    int gS1 = ((n + 1) / 2 + 3) / 4;   // node pairs, 4 waves/block
    int gS2 = (n + 31) / 32;

    k_hist<<<256, 256, 0, stream>>>(ei, flag, gbcnt, E);
    k_scanB<<<1, NB, 0, stream>>>(gbcnt, bbase, bcursor, E);
    k_scatter<<<gT, 256, 0, stream>>>(ei, flag, bcursor, rec, E);
    k_csr<<<NB, 256, 0, stream>>>(rec, bbase, rp, col, dinv, E);
    k_gemm1<<<(n + 63) / 64, 256, 0, stream>>>(x, Bf, dinv, xws, n);
    k_spmm1<<<gS1, 256, 0, stream>>>((const __half2*)xws, rp, col, dinv, b1, W2, hw2s, n);
    k_spmm2<<<gS2, 256, 0, stream>>>(rp, col, dinv, hw2s, b2, Wc, bc, out, n);
}

// Round 13
// 177.817 us; speedup vs baseline: 2.6630x; 1.0636x over previous
//
#include <hip/hip_runtime.h>
#include <hip/hip_fp16.h>
#include <stdint.h>

#define NN 100000
#define NB 512
#define BUCKET 196   // ceil(NN/NB)
#define TILE 4096
#define EPT 16       // TILE / 256

typedef _Float16 f16x8 __attribute__((ext_vector_type(8)));
typedef float f32x4  __attribute__((ext_vector_type(4)));

__device__ __forceinline__ int edge_at(const void* p, int f64, long long idx){
    return f64 ? (int)((const long long*)p)[idx] : ((const int*)p)[idx];
}
__device__ __forceinline__ __half2 u2h(unsigned u){ return *(__half2*)&u; }

// ---------- graph preprocessing ----------

__global__ void k_detect(const void* __restrict__ ep, int* flag, long long nwords, long long nn){
    __shared__ int bad;
    if (threadIdx.x == 0) bad = 0;
    __syncthreads();
    const long long* p = (const long long*)ep;
    for (long long i = threadIdx.x; i < 1024 && i < nwords; i += blockDim.x){
        long long v = p[i];
        if (v < 0 || v >= nn) atomicOr(&bad, 1);
    }
    __syncthreads();
    if (threadIdx.x == 0) flag[0] = bad ? 0 : 1;  // 1 => int64
}

__global__ __launch_bounds__(256) void k_hist(const void* __restrict__ ep, const int* __restrict__ flag,
                                              int* __restrict__ gbcnt, int E){
    __shared__ int h[NB];
    for (int i = threadIdx.x; i < NB; i += 256) h[i] = 0;
    __syncthreads();
    int f = flag[0];
    for (long long e = blockIdx.x * 256 + threadIdx.x; e < E; e += (long long)gridDim.x * 256){
        int d = edge_at(ep, f, (long long)E + e);
        atomicAdd(&h[d / BUCKET], 1);
    }
    __syncthreads();
    for (int i = threadIdx.x; i < NB; i += 256)
        if (h[i]) atomicAdd(&gbcnt[i], h[i]);
}

__global__ void k_scanB(const int* __restrict__ gbcnt, int* __restrict__ bbase,
                        int* __restrict__ bcursor, int E){
    __shared__ int sh[NB];
    int t = threadIdx.x;
    int own = gbcnt[t];
    sh[t] = own; __syncthreads();
    for (int off = 1; off < NB; off <<= 1){
        int u = (t >= off) ? sh[t - off] : 0;
        __syncthreads();
        sh[t] += u;
        __syncthreads();
    }
    int excl = sh[t] - own;
    bbase[t] = excl;
    bcursor[t] = excl;
    if (t == NB - 1) bbase[NB] = excl + own;
    (void)E;
}

// LDS-staged scatter: rank -> compact into LDS -> per-bucket coalesced flush.
__global__ __launch_bounds__(256) void k_scatter(const void* __restrict__ ep, const int* __restrict__ flag,
                                                 int* __restrict__ bcursor, uint2* __restrict__ rec, int E){
    __shared__ int h[NB];
    __shared__ int gb[NB];
    __shared__ int lo[NB];
    __shared__ int sc[256];
    __shared__ uint2 staged[TILE];
    __shared__ int sdst[TILE];
    int t = threadIdx.x;
    int f = flag[0];
    long long base = (long long)blockIdx.x * TILE;
    for (int i = t; i < NB; i += 256) h[i] = 0;
    __syncthreads();
    int s[EPT], d[EPT], r[EPT], bb[EPT];
    #pragma unroll
    for (int j = 0; j < EPT; ++j){
        long long e = base + j * 256 + t;
        if (e < E){
            s[j]  = edge_at(ep, f, e);
            d[j]  = edge_at(ep, f, (long long)E + e);
            bb[j] = d[j] / BUCKET;
            r[j]  = atomicAdd(&h[bb[j]], 1);
        }
    }
    __syncthreads();
    {
        int b0 = 2 * t, b1i = b0 + 1;
        int own = h[b0] + h[b1i];
        sc[t] = own; __syncthreads();
        for (int off = 1; off < 256; off <<= 1){
            int u = (t >= off) ? sc[t - off] : 0;
            __syncthreads();
            sc[t] += u;
            __syncthreads();
        }
        int excl = sc[t] - own;
        lo[b0]  = excl;
        lo[b1i] = excl + h[b0];
    }
    for (int i = t; i < NB; i += 256)
        gb[i] = h[i] ? atomicAdd(&bcursor[i], h[i]) : 0;
    __syncthreads();
    #pragma unroll
    for (int j = 0; j < EPT; ++j){
        long long e = base + j * 256 + t;
        if (e < E){
            int slot = lo[bb[j]] + r[j];
            staged[slot] = make_uint2((unsigned)s[j], (unsigned)d[j]);
            sdst[slot]   = gb[bb[j]] + r[j];
        }
    }
    __syncthreads();
    int cnt = (E - base < TILE) ? (int)(E - base) : TILE;
    for (int q = t; q < cnt; q += 256)
        rec[sdst[q]] = staged[q];
}

__global__ __launch_bounds__(256) void k_csr(const uint2* __restrict__ rec, const int* __restrict__ bbase,
                                             int* __restrict__ rp, int* __restrict__ col,
                                             float* __restrict__ dinv, int E){
    int b = blockIdx.x;
    int t = threadIdx.x;
    if (b == 0 && t == 0) rp[NN] = E;
    int d0 = b * BUCKET;
    if (d0 >= NN) return;
    int e0 = bbase[b], e1 = bbase[b + 1];
    __shared__ int h[BUCKET];
    __shared__ int sc[256];
    __shared__ int cur[BUCKET];
    for (int i = t; i < BUCKET; i += 256) h[i] = 0;
    __syncthreads();
    for (int e = e0 + t; e < e1; e += 256)
        atomicAdd(&h[rec[e].y - d0], 1);
    __syncthreads();
    int own = (t < BUCKET) ? h[t] : 0;
    sc[t] = own; __syncthreads();
    for (int off = 1; off < 256; off <<= 1){
        int u = (t >= off) ? sc[t - off] : 0;
        __syncthreads();
        sc[t] += u;
        __syncthreads();
    }
    int excl = sc[t] - own;
    if (t < BUCKET && d0 + t < NN){
        rp[d0 + t]   = e0 + excl;
        cur[t]       = e0 + excl;
        dinv[d0 + t] = rsqrtf((float)(own + 1));
    }
    __syncthreads();
    for (int e = e0 + t; e < e1; e += 256){
        uint2 u = rec[e];
        int p = atomicAdd(&cur[u.y - d0], 1);
        col[p] = (int)u.x;
    }
}

// ---------- GEMM1 via single-term fp16 MFMA ----------

__global__ __launch_bounds__(256) void k_prepW(const float* __restrict__ W1, _Float16* __restrict__ Bf){
    int q = blockIdx.x * 256 + threadIdx.x;   // 192*128 = 24576
    if (q >= 192 * 128) return;
    int k = q >> 7, c = q & 127;
    float w = (k < 165) ? W1[k * 128 + c] : 0.0f;
    int tt = k >> 5, kk = k & 31;
    int lane = ((kk >> 3) << 4) + (c & 15);
    int j = kk & 7;
    int f = c >> 4;
    int idx = (((tt * 8 + f) * 64 + lane) << 3) + j;
    Bf[idx] = (_Float16)w;
}

// C = (x @ W1) * dinv, stored fp16 ROW-MAJOR [node][128], full-line epilogue.
#define ASTRIDE 200   // fp16 elems; 400B row stride
#define CSTRIDE 136   // fp16 elems; C-tile stride (16B-aligned rows)
__global__ __launch_bounds__(256, 4) void k_gemm1(const float* __restrict__ x,
                                                  const _Float16* __restrict__ Bf16,
                                                  const float* __restrict__ dinv,
                                                  _Float16* __restrict__ xws, int n){
    __shared__ _Float16 Ah[64 * ASTRIDE];
    int t = threadIdx.x;
    int w = t >> 6, lane = t & 63;
    int i0 = blockIdx.x * 64;

    for (int q = t; q < 64 * 27; q += 256){
        int r = q / 27, k = 165 + (q - r * 27);
        Ah[r * ASTRIDE + k] = (_Float16)0.0f;
    }

    f16x8 Bf[6][2];
    #pragma unroll
    for (int tt = 0; tt < 6; ++tt)
        #pragma unroll
        for (int cf = 0; cf < 2; ++cf)
            Bf[tt][cf] = *(const f16x8*)&Bf16[((tt * 8 + (w * 2 + cf)) * 64 + lane) << 3];

    {
        const float* src = x + (size_t)i0 * 165;
        int nElem = n - i0;
        nElem = (nElem > 64 ? 64 : nElem) * 165;
        #pragma unroll
        for (int b = 0; b < 7; ++b){
            float v[6];
            #pragma unroll
            for (int u = 0; u < 6; ++u){
                int idx = t + (b * 6 + u) * 256;
                v[u] = (idx < nElem) ? src[idx] : 0.0f;
            }
            #pragma unroll
            for (int u = 0; u < 6; ++u){
                int idx = t + (b * 6 + u) * 256;
                if (idx < 64 * 165){
                    int r = idx / 165;
                    int k = idx - r * 165;
                    Ah[r * ASTRIDE + k] = (_Float16)v[u];
                }
            }
        }
    }

    f32x4 acc[4][2];
    #pragma unroll
    for (int m = 0; m < 4; ++m){ acc[m][0] = (f32x4)0.0f; acc[m][1] = (f32x4)0.0f; }

    __syncthreads();

    int rl = lane & 15, kl = (lane >> 4) * 8;
    #pragma unroll
    for (int tt = 0; tt < 6; ++tt){
        f16x8 ah[4];
        #pragma unroll
        for (int m = 0; m < 4; ++m)
            ah[m] = *(const f16x8*)&Ah[(m * 16 + rl) * ASTRIDE + tt * 32 + kl];
        #pragma unroll
        for (int m = 0; m < 4; ++m)
            #pragma unroll
            for (int cf = 0; cf < 2; ++cf)
                acc[m][cf] = __builtin_amdgcn_mfma_f32_16x16x32_f16(ah[m], Bf[tt][cf], acc[m][cf], 0, 0, 0);
    }

    __syncthreads();
    _Float16* Cs = (_Float16*)Ah;
    #pragma unroll
    for (int m = 0; m < 4; ++m){
        int rloc = m * 16 + (lane >> 4) * 4;
        #pragma unroll
        for (int r = 0; r < 4; ++r){
            int row = i0 + rloc + r;
            float dvv = (row < n) ? dinv[row] : 0.0f;
            #pragma unroll
            for (int cf = 0; cf < 2; ++cf){
                int colg = w * 32 + cf * 16 + (lane & 15);
                Cs[(rloc + r) * CSTRIDE + colg] = (_Float16)(acc[m][cf][r] * dvv);
            }
        }
    }
    __syncthreads();
    int nrow = (i0 + 64 <= n) ? 64 : (n - i0);
    for (int q = t; q < nrow * 16; q += 256){
        int row = q >> 4, cw = q & 15;
        uint4 vv = *(const uint4*)&Cs[row * CSTRIDE + cw * 8];
        *(uint4*)&xws[((size_t)(i0 + row)) * 128 + cw * 8] = vv;
    }
}

// ---------- SpMM layer 1: 1 node/wave, 8B lanes -> 2 rows per gather instr ----------
// Lanes 0-31 process even edges of a chunk, lanes 32-63 odd edges; lane handles
// feature quad (lane&31): uint2 = 2 half2 = 4 fp16. 16-edge chunks: 8 gathers of
// 512B in flight, unguarded; guarded tail. Cross-half combine via shfl_xor(32).
__global__ __launch_bounds__(256) void k_spmm1(const uint2* __restrict__ xg, const int* __restrict__ rp,
                                               const int* __restrict__ col, const float* __restrict__ dinv,
                                               const float* __restrict__ b1, const float* __restrict__ W2,
                                               float* __restrict__ hw2s, int n){
    int i = (blockIdx.x * 256 + threadIdx.x) >> 6;
    int lane = threadIdx.x & 63;
    if (i >= n) return;
    int e0 = rp[i], e1 = rp[i + 1];
    float di = dinv[i];
    int lf = lane & 31;
    int hi = lane >> 5;
    __half2 a0 = __float2half2_rn(0.0f), a1 = a0;
    if (lane < 32){                                    // self loop counted once
        uint2 v = xg[(size_t)i * 32 + lf];
        a0 = u2h(v.x); a1 = u2h(v.y);
    }
    int e = e0;
    for (; e + 16 <= e1; e += 16){
        int c = col[e + lane];                         // lanes 0..15 valid
        #pragma unroll
        for (int k = 0; k < 8; ++k){
            int sL = __builtin_amdgcn_readlane(c, 2 * k);
            int sH = __builtin_amdgcn_readlane(c, 2 * k + 1);
            int s = hi ? sH : sL;
            uint2 v = xg[(size_t)s * 32 + lf];
            a0 = __hadd2(a0, u2h(v.x));
            a1 = __hadd2(a1, u2h(v.y));
        }
    }
    int rem = e1 - e;
    if (rem > 0){
        int c = (lane < rem) ? col[e + lane] : 0;
        #pragma unroll
        for (int k = 0; k < 8; ++k){
            int sL = __builtin_amdgcn_readlane(c, 2 * k);
            int sH = __builtin_amdgcn_readlane(c, 2 * k + 1);
            int s = hi ? sH : sL;
            uint2 v = xg[(size_t)s * 32 + lf];
            if (2 * k + hi < rem){
                a0 = __hadd2(a0, u2h(v.x));
                a1 = __hadd2(a1, u2h(v.y));
            }
        }
    }
    // combine the two halves (feature quad lf duplicated in lanes lf and lf+32)
    {
        int u0 = __shfl_xor(*(int*)&a0, 32);
        int u1 = __shfl_xor(*(int*)&a1, 32);
        a0 = __hadd2(a0, u2h((unsigned)u0));
        a1 = __hadd2(a1, u2h((unsigned)u1));
    }
    int f0 = 4 * lf;
    float4 bv = *(const float4*)(b1 + f0);
    float h0 = fmaxf(di * __low2float(a0)  + bv.x, 0.0f);
    float h1 = fmaxf(di * __high2float(a0) + bv.y, 0.0f);
    float h2 = fmaxf(di * __low2float(a1)  + bv.z, 0.0f);
    float h3 = fmaxf(di * __high2float(a1) + bv.w, 0.0f);
    float4 w01 = *(const float4*)(W2 + 2 * f0);        // W2[f0][0..1], W2[f0+1][0..1]
    float4 w23 = *(const float4*)(W2 + 2 * f0 + 4);
    float s0 = h0 * w01.x + h1 * w01.z + h2 * w23.x + h3 * w23.z;
    float s1 = h0 * w01.y + h1 * w01.w + h2 * w23.y + h3 * w23.w;
    #pragma unroll
    for (int off = 1; off < 32; off <<= 1){
        s0 += __shfl_xor(s0, off);
        s1 += __shfl_xor(s1, off);
    }
    if (lane == 0)
        *(float2*)(hw2s + 2 * i) = make_float2(s0 * di, s1 * di);
}

// ---------- SpMM layer 2: wave = 8 nodes, lane j strides edges ----------
__global__ __launch_bounds__(256) void k_spmm2(const int* __restrict__ rp, const int* __restrict__ col,
                                               const float* __restrict__ dinv, const float* __restrict__ hw2s,
                                               const float* __restrict__ b2, const float* __restrict__ Wc,
                                               const float* __restrict__ bc, float* __restrict__ out, int n){
    int wave = threadIdx.x >> 6, lane = threadIdx.x & 63;
    int g = lane >> 3, j = lane & 7;
    int node = blockIdx.x * 32 + wave * 8 + g;
    if (node >= n) return;
    int e0 = rp[node], e1 = rp[node + 1];
    float s0 = 0.0f, s1 = 0.0f;
    if (j == 0){ s0 = hw2s[2 * node]; s1 = hw2s[2 * node + 1]; }
    for (int e = e0 + j; e < e1; e += 8){
        int c = col[e];
        float2 v = *(const float2*)(hw2s + 2 * c);
        s0 += v.x; s1 += v.y;
    }
    #pragma unroll
    for (int off = 1; off < 8; off <<= 1){
        s0 += __shfl_xor(s0, off);
        s1 += __shfl_xor(s1, off);
    }
    if (j == 0){
        float di = dinv[node];
        float a0 = fmaxf(di * s0 + b2[0], 0.0f);
        float a1 = fmaxf(di * s1 + b2[1], 0.0f);
        float z = a0 * Wc[0] + a1 * Wc[1] + bc[0];
        out[node] = 1.0f / (1.0f + expf(-z));
    }
}

extern "C" void kernel_launch(void* const* d_in, const int* in_sizes, int n_in,
                              void* d_out, int out_size, void* d_ws, size_t ws_size,
                              hipStream_t stream) {
    const float* x  = (const float*)d_in[0];
    const void*  ei = d_in[1];
    const float* W1 = (const float*)d_in[2];
    const float* b1 = (const float*)d_in[3];
    const float* W2 = (const float*)d_in[4];
    const float* b2 = (const float*)d_in[5];
    const float* Wc = (const float*)d_in[6];
    const float* bc = (const float*)d_in[7];
    float* out = (float*)d_out;

    const int n = NN;
    const int E = in_sizes[1] / 2;

    char* ws = (char*)d_ws;
    size_t off = 0;
    auto alloc = [&](size_t bytes)->char*{
        off = (off + 255) & ~(size_t)255;
        char* p = ws + off; off += bytes; return p;
    };
    int*      flag    = (int*)alloc(4);
    int*      gbcnt   = (int*)alloc((size_t)NB * 4);
    int*      bbase   = (int*)alloc((size_t)(NB + 1) * 4);
    int*      bcursor = (int*)alloc((size_t)NB * 4);
    int*      rp      = (int*)alloc((size_t)(n + 1) * 4);
    float*    dinv    = (float*)alloc((size_t)n * 4);
    float*    hw2s    = (float*)alloc((size_t)n * 2 * 4);
    _Float16* Bf      = (_Float16*)alloc((size_t)192 * 128 * 2);
    int*      col     = (int*)alloc((size_t)E * 4);
    uint2*    rec     = (uint2*)alloc((size_t)E * 8);
    _Float16* xws;
    {
        size_t xws_bytes = (size_t)n * 128 * 2;
        size_t off_sep = (off + 255) & ~(size_t)255;
        if (off_sep + xws_bytes <= ws_size) xws = (_Float16*)alloc(xws_bytes);
        else                                xws = (_Float16*)rec;
    }
    (void)n_in; (void)out_size;

    hipMemsetAsync(gbcnt, 0, (size_t)NB * 4, stream);
    k_detect<<<1, 256, 0, stream>>>(ei, flag, (long long)E, (long long)n);
    k_prepW<<<96, 256, 0, stream>>>(W1, Bf);

    int gT = (E + TILE - 1) / TILE;
    int gS1 = (n + 3) / 4;            // 1 node per wave, 4 waves/block
    int gS2 = (n + 31) / 32;

    k_hist<<<256, 256, 0, stream>>>(ei, flag, gbcnt, E);
    k_scanB<<<1, NB, 0, stream>>>(gbcnt, bbase, bcursor, E);
    k_scatter<<<gT, 256, 0, stream>>>(ei, flag, bcursor, rec, E);
    k_csr<<<NB, 256, 0, stream>>>(rec, bbase, rp, col, dinv, E);
    k_gemm1<<<(n + 63) / 64, 256, 0, stream>>>(x, Bf, dinv, xws, n);
    k_spmm1<<<gS1, 256, 0, stream>>>((const uint2*)xws, rp, col, dinv, b1, W2, hw2s, n);
    k_spmm2<<<gS2, 256, 0, stream>>>(rp, col, dinv, hw2s, b2, Wc, bc, out, n);
}